// Round 3
// baseline (836.408 us; speedup 1.0000x reference)
//
#include <hip/hip_runtime.h>

#define BB 4
#define LL 4096
#define DD 256

typedef short bf16x8 __attribute__((ext_vector_type(8)));
typedef float f32x4 __attribute__((ext_vector_type(4)));
typedef unsigned short u16;

__device__ inline u16 f2b(float f) {
    union { float f; unsigned u; } v; v.f = f;
    unsigned r = (v.u + 0x7fffu + ((v.u >> 16) & 1u)) >> 16;  // RNE
    return (u16)r;
}

__device__ inline f32x4 mfma16(bf16x8 a, bf16x8 b, f32x4 c) {
    return __builtin_amdgcn_mfma_f32_16x16x32_bf16(a, b, c, 0, 0, 0);
}

// ---------------------------------------------------------------------------
// Kernel 0: convert the 4 weight matrices fp32 -> bf16. 65536 threads.
// ---------------------------------------------------------------------------
__global__ __launch_bounds__(256) void wconv_kernel(
    const float* __restrict__ Wq, const float* __restrict__ Wk,
    const float* __restrict__ Wv, const float* __restrict__ Wo,
    u16* __restrict__ wqb, u16* __restrict__ wkb,
    u16* __restrict__ wvb, u16* __restrict__ wob)
{
    int i = blockIdx.x * 256 + threadIdx.x;   // 0 .. 65535
    wqb[i] = f2b(Wq[i]);
    wkb[i] = f2b(Wk[i]);
    wvb[i] = f2b(Wv[i]);
    wob[i] = f2b(Wv == Wv ? Wv[i] : 0.f);     // placeholder; fixed below
}

// NOTE: wconv above must convert Wo into wob — rewritten correctly here.
__global__ __launch_bounds__(256) void wconv2_kernel(
    const float* __restrict__ Wo, u16* __restrict__ wob)
{
    int i = blockIdx.x * 256 + threadIdx.x;
    wob[i] = f2b(Wo[i]);
}

// ---------------------------------------------------------------------------
// Kernel 1: fused QKV projection via MFMA. 512 blocks: (row-group of 64) x
// (col-half of 128). Wave w computes rows [g*64 + 16w, +16) x 128 cols for
// Wq, Wk, Wv. NT GEMM, A-frag from x (fp32->bf16 on the fly).
// V stored TRANSPOSED: vtb[b][d][l].
// ---------------------------------------------------------------------------
__global__ __launch_bounds__(256, 2) void qkv_kernel(
    const float* __restrict__ x,
    const u16* __restrict__ wqb, const u16* __restrict__ wkb, const u16* __restrict__ wvb,
    u16* __restrict__ qb, u16* __restrict__ kb, u16* __restrict__ vtb)
{
    const int w = threadIdx.x >> 6, lane = threadIdx.x & 63;
    const int q4 = lane >> 4, ln = lane & 15;
    const int g = blockIdx.x >> 1, half = blockIdx.x & 1;
    const int m_base = g * 64 + w * 16;
    const int c_base = half * 128;

    bf16x8 a[8];
    const float* xrow = x + (size_t)(m_base + ln) * DD;
    #pragma unroll
    for (int ks = 0; ks < 8; ++ks) {
        const float4* p = (const float4*)(xrow + ks * 32 + q4 * 8);
        float4 f0 = p[0], f1 = p[1];
        bf16x8 t;
        t[0] = (short)f2b(f0.x); t[1] = (short)f2b(f0.y);
        t[2] = (short)f2b(f0.z); t[3] = (short)f2b(f0.w);
        t[4] = (short)f2b(f1.x); t[5] = (short)f2b(f1.y);
        t[6] = (short)f2b(f1.z); t[7] = (short)f2b(f1.w);
        a[ks] = t;
    }

    const u16* ws[3] = {wqb, wkb, wvb};
    for (int wi = 0; wi < 3; ++wi) {
        const u16* W = ws[wi];
        f32x4 acc[8];
        #pragma unroll
        for (int ct = 0; ct < 8; ++ct) acc[ct] = f32x4{0.f, 0.f, 0.f, 0.f};
        #pragma unroll
        for (int ks = 0; ks < 8; ++ks) {
            #pragma unroll
            for (int ct = 0; ct < 8; ++ct) {
                bf16x8 bf = *(const bf16x8*)(W + (size_t)(c_base + ct * 16 + ln) * DD + ks * 32 + q4 * 8);
                acc[ct] = mfma16(a[ks], bf, acc[ct]);
            }
        }
        if (wi < 2) {
            u16* dst = (wi == 0) ? qb : kb;
            #pragma unroll
            for (int ct = 0; ct < 8; ++ct)
                #pragma unroll
                for (int r = 0; r < 4; ++r) {
                    int row = m_base + q4 * 4 + r;
                    int col = c_base + ct * 16 + ln;
                    dst[(size_t)row * DD + col] = f2b(acc[ct][r]);
                }
        } else {
            #pragma unroll
            for (int ct = 0; ct < 8; ++ct)
                #pragma unroll
                for (int r = 0; r < 4; ++r) {
                    int row = m_base + q4 * 4 + r;       // global M = b*L + l
                    int col = c_base + ct * 16 + ln;     // d
                    int bb = row >> 12, l = row & 4095;
                    vtb[(size_t)bb * (DD * LL) + (size_t)col * LL + l] = f2b(acc[ct][r]);
                }
        }
    }
}

// ---------------------------------------------------------------------------
// Kernel 2: causal ReLU attention, MFMA flash-style, pipelined.
// 512 blocks (2 per CU): block handles ONE 32-row q-tile t of batch b.
// Index map pairs long+short tiles onto the same CU: co-resident blocks
// 2c,2c+1 get tiles p and 127-p -> 129 k-tile units per CU slot.
// Per k-tile (32 keys):
//   S = Q Kt (K-frags double-buffered in regs, prefetched 1 iter ahead)
//   P = relu(mask(S))/max(l,1) -> bf16 -> LDS (parity double-buffer)
//   one barrier
//   O += P V (V^T-frags loaded at top of iteration, land during S phase)
// ---------------------------------------------------------------------------
#define LSTRIDE 40   // LDS row stride in shorts (padded: 80B, 16B-aligned)

__global__ __launch_bounds__(256, 2) void attn_kernel(
    const u16* __restrict__ qb, const u16* __restrict__ kb,
    const u16* __restrict__ vtb, u16* __restrict__ ctxb)
{
    __shared__ u16 ps[2][32 * LSTRIDE];

    const int i = blockIdx.x;
    const int b = (i >> 1) & 3;
    const int p = i >> 3;
    const int t = (i & 1) ? p : 127 - p;

    const int w = threadIdx.x >> 6, lane = threadIdx.x & 63;
    const int q4 = lane >> 4, ln = lane & 15;
    const int wr = w >> 1, wc = w & 1;

    const u16* qB = qb + (size_t)b * LL * DD;
    const u16* kB = kb + (size_t)b * LL * DD;
    const u16* vB = vtb + (size_t)b * DD * LL;

    // Q A-fragments, resident: rows [32t + 16wr, +16)
    bf16x8 aQ[8];
    {
        const u16* q0 = qB + (size_t)(t * 32 + wr * 16 + ln) * DD;
        #pragma unroll
        for (int ks = 0; ks < 8; ++ks)
            aQ[ks] = *(const bf16x8*)(q0 + ks * 32 + q4 * 8);
    }

    f32x4 oacc[8];
    #pragma unroll
    for (int tt = 0; tt < 8; ++tt) oacc[tt] = f32x4{0.f, 0.f, 0.f, 0.f};

    float inv[4];
    #pragma unroll
    for (int r = 0; r < 4; ++r) {
        int row = t * 32 + wr * 16 + q4 * 4 + r;
        inv[r] = 1.0f / (float)(row > 1 ? row : 1);
    }

    const int rowl = wr * 16 + q4 * 4;
    const int coll = wc * 16 + ln;

    // K-frag double buffer: preload kt=0
    bf16x8 kf[2][8];
    {
        const u16* krow = kB + (size_t)(wc * 16 + ln) * DD;
        #pragma unroll
        for (int ks = 0; ks < 8; ++ks)
            kf[0][ks] = *(const bf16x8*)(krow + ks * 32 + q4 * 8);
    }

    #pragma unroll 2
    for (int kt = 0; kt <= t; ++kt) {
        const int cur = kt & 1, nxt = cur ^ 1;

        // ---- V-frags for THIS kt: issued first, consumed after barrier ----
        bf16x8 vf[8];
        #pragma unroll
        for (int tt = 0; tt < 8; ++tt)
            vf[tt] = *(const bf16x8*)(vB + (size_t)(wc * 128 + tt * 16 + ln) * LL + kt * 32 + q4 * 8);

        // ---- K-frags for NEXT kt: in flight across the whole iteration ----
        {
            const int ktn = (kt < t) ? (kt + 1) : kt;
            const u16* krow = kB + (size_t)(ktn * 32 + wc * 16 + ln) * DD;
            #pragma unroll
            for (int ks = 0; ks < 8; ++ks)
                kf[nxt][ks] = *(const bf16x8*)(krow + ks * 32 + q4 * 8);
        }

        // ---- S phase: two independent 4-MFMA chains ----
        f32x4 sa = f32x4{0.f, 0.f, 0.f, 0.f};
        f32x4 sb = f32x4{0.f, 0.f, 0.f, 0.f};
        #pragma unroll
        for (int ks = 0; ks < 4; ++ks) {
            sa = mfma16(aQ[2 * ks], kf[cur][2 * ks], sa);
            sb = mfma16(aQ[2 * ks + 1], kf[cur][2 * ks + 1], sb);
        }

        // ---- mask / relu / scale -> LDS (parity buffer) ----
        const bool diag = (kt == t);
        #pragma unroll
        for (int r = 0; r < 4; ++r) {
            float v = fmaxf(sa[r] + sb[r], 0.f) * inv[r];
            if (diag && (coll > rowl + r)) v = 0.f;
            ps[cur][(rowl + r) * LSTRIDE + coll] = f2b(v);
        }
        __syncthreads();

        // ---- PV phase ----
        bf16x8 ap = *(const bf16x8*)(&ps[cur][(wr * 16 + ln) * LSTRIDE + q4 * 8]);
        #pragma unroll
        for (int tt = 0; tt < 8; ++tt)
            oacc[tt] = mfma16(ap, vf[tt], oacc[tt]);
        // no second barrier: next iteration writes ps[nxt]; ps[cur] is only
        // rewritten at kt+2, after the kt+1 barrier.
    }

    // ---- epilogue: store ctx (bf16) ----
    #pragma unroll
    for (int tt = 0; tt < 8; ++tt)
        #pragma unroll
        for (int r = 0; r < 4; ++r) {
            int row = t * 32 + wr * 16 + q4 * 4 + r;
            int col = wc * 128 + tt * 16 + ln;
            ctxb[((size_t)b * LL + row) * DD + col] = f2b(oacc[tt][r]);
        }
}

// ---------------------------------------------------------------------------
// Kernel 3: output projection via MFMA (ctx bf16 @ Wo^T), fp32 store.
// 512 blocks: (row-group of 64) x (col-half of 128).
// ---------------------------------------------------------------------------
__global__ __launch_bounds__(256, 2) void oproj_kernel(
    const u16* __restrict__ ctxb, const u16* __restrict__ wob,
    float* __restrict__ out)
{
    const int w = threadIdx.x >> 6, lane = threadIdx.x & 63;
    const int q4 = lane >> 4, ln = lane & 15;
    const int g = blockIdx.x >> 1, half = blockIdx.x & 1;
    const int m_base = g * 64 + w * 16;
    const int c_base = half * 128;

    bf16x8 a[8];
    const u16* crow = ctxb + (size_t)(m_base + ln) * DD;
    #pragma unroll
    for (int ks = 0; ks < 8; ++ks)
        a[ks] = *(const bf16x8*)(crow + ks * 32 + q4 * 8);

    f32x4 acc[8];
    #pragma unroll
    for (int ct = 0; ct < 8; ++ct) acc[ct] = f32x4{0.f, 0.f, 0.f, 0.f};
    #pragma unroll
    for (int ks = 0; ks < 8; ++ks) {
        #pragma unroll
        for (int ct = 0; ct < 8; ++ct) {
            bf16x8 bf = *(const bf16x8*)(wob + (size_t)(c_base + ct * 16 + ln) * DD + ks * 32 + q4 * 8);
            acc[ct] = mfma16(a[ks], bf, acc[ct]);
        }
    }
    #pragma unroll
    for (int ct = 0; ct < 8; ++ct)
        #pragma unroll
        for (int r = 0; r < 4; ++r) {
            int row = m_base + q4 * 4 + r;
            int col = c_base + ct * 16 + ln;
            out[(size_t)row * DD + col] = acc[ct][r];
        }
}

extern "C" void kernel_launch(void* const* d_in, const int* in_sizes, int n_in,
                              void* d_out, int out_size, void* d_ws, size_t ws_size,
                              hipStream_t stream)
{
    const float* x  = (const float*)d_in[0];
    const float* Wq = (const float*)d_in[1];
    const float* Wk = (const float*)d_in[2];
    const float* Wv = (const float*)d_in[3];
    const float* Wo = (const float*)d_in[4];
    float* out = (float*)d_out;

    const size_t nW = (size_t)DD * DD;        // 65536
    const size_t nX = (size_t)BB * LL * DD;   // 4,194,304

    u16* wqb  = (u16*)d_ws;
    u16* wkb  = wqb + nW;
    u16* wvb  = wkb + nW;
    u16* wob  = wvb + nW;
    u16* qb   = wob + nW;
    u16* kb   = qb + nX;
    u16* vtb  = kb + nX;        // transposed: [B][D][L]
    u16* ctxb = vtb + nX;       // total ~34 MB

    wconv_kernel<<<dim3(DD * DD / 256), dim3(256), 0, stream>>>(
        Wq, Wk, Wv, Wo, wqb, wkb, wvb, wob);
    wconv2_kernel<<<dim3(DD * DD / 256), dim3(256), 0, stream>>>(Wo, wob);
    qkv_kernel<<<dim3(2 * BB * LL / 64), dim3(256), 0, stream>>>(
        x, wqb, wkb, wvb, qb, kb, vtb);
    attn_kernel<<<dim3(512), dim3(256), 0, stream>>>(qb, kb, vtb, ctxb);
    oproj_kernel<<<dim3(2 * BB * LL / 64), dim3(256), 0, stream>>>(ctxb, wob, out);
}

// Round 4
// 550.794 us; speedup vs baseline: 1.5186x; 1.5186x over previous
//
#include <hip/hip_runtime.h>

#define BB 4
#define LL 4096
#define DD 256

typedef short bf16x8 __attribute__((ext_vector_type(8)));
typedef float f32x4 __attribute__((ext_vector_type(4)));
typedef unsigned short u16;

__device__ inline u16 f2b(float f) {
    union { float f; unsigned u; } v; v.f = f;
    unsigned r = (v.u + 0x7fffu + ((v.u >> 16) & 1u)) >> 16;  // RNE
    return (u16)r;
}

__device__ inline f32x4 mfma16(bf16x8 a, bf16x8 b, f32x4 c) {
    return __builtin_amdgcn_mfma_f32_16x16x32_bf16(a, b, c, 0, 0, 0);
}

// ---------------------------------------------------------------------------
// Kernel 0: convert the 4 weight matrices fp32 -> bf16. 65536 threads.
// ---------------------------------------------------------------------------
__global__ __launch_bounds__(256) void wconv_kernel(
    const float* __restrict__ Wq, const float* __restrict__ Wk,
    const float* __restrict__ Wv, const float* __restrict__ Wo,
    u16* __restrict__ wqb, u16* __restrict__ wkb,
    u16* __restrict__ wvb, u16* __restrict__ wob)
{
    int i = blockIdx.x * 256 + threadIdx.x;   // 0 .. 65535
    wqb[i] = f2b(Wq[i]);
    wkb[i] = f2b(Wk[i]);
    wvb[i] = f2b(Wv[i]);
    wob[i] = f2b(Wo[i]);
}

// ---------------------------------------------------------------------------
// Kernel 1: fused QKV projection via MFMA. 512 blocks: (row-group of 64) x
// (col-half of 128). Wave w computes rows [g*64 + 16w, +16) x 128 cols for
// Wq, Wk, Wv. NT GEMM, A-frag from x (fp32->bf16 on the fly).
// V stored TRANSPOSED: vtb[b][d][l].
// ---------------------------------------------------------------------------
__global__ __launch_bounds__(256, 2) void qkv_kernel(
    const float* __restrict__ x,
    const u16* __restrict__ wqb, const u16* __restrict__ wkb, const u16* __restrict__ wvb,
    u16* __restrict__ qb, u16* __restrict__ kb, u16* __restrict__ vtb)
{
    const int w = threadIdx.x >> 6, lane = threadIdx.x & 63;
    const int q4 = lane >> 4, ln = lane & 15;
    const int g = blockIdx.x >> 1, half = blockIdx.x & 1;
    const int m_base = g * 64 + w * 16;
    const int c_base = half * 128;

    bf16x8 a[8];
    const float* xrow = x + (size_t)(m_base + ln) * DD;
    #pragma unroll
    for (int ks = 0; ks < 8; ++ks) {
        const float4* p = (const float4*)(xrow + ks * 32 + q4 * 8);
        float4 f0 = p[0], f1 = p[1];
        bf16x8 t;
        t[0] = (short)f2b(f0.x); t[1] = (short)f2b(f0.y);
        t[2] = (short)f2b(f0.z); t[3] = (short)f2b(f0.w);
        t[4] = (short)f2b(f1.x); t[5] = (short)f2b(f1.y);
        t[6] = (short)f2b(f1.z); t[7] = (short)f2b(f1.w);
        a[ks] = t;
    }

    const u16* ws[3] = {wqb, wkb, wvb};
    for (int wi = 0; wi < 3; ++wi) {
        const u16* W = ws[wi];
        f32x4 acc[8];
        #pragma unroll
        for (int ct = 0; ct < 8; ++ct) acc[ct] = f32x4{0.f, 0.f, 0.f, 0.f};
        #pragma unroll
        for (int ks = 0; ks < 8; ++ks) {
            #pragma unroll
            for (int ct = 0; ct < 8; ++ct) {
                bf16x8 bf = *(const bf16x8*)(W + (size_t)(c_base + ct * 16 + ln) * DD + ks * 32 + q4 * 8);
                acc[ct] = mfma16(a[ks], bf, acc[ct]);
            }
        }
        if (wi < 2) {
            u16* dst = (wi == 0) ? qb : kb;
            #pragma unroll
            for (int ct = 0; ct < 8; ++ct)
                #pragma unroll
                for (int r = 0; r < 4; ++r) {
                    int row = m_base + q4 * 4 + r;
                    int col = c_base + ct * 16 + ln;
                    dst[(size_t)row * DD + col] = f2b(acc[ct][r]);
                }
        } else {
            #pragma unroll
            for (int ct = 0; ct < 8; ++ct)
                #pragma unroll
                for (int r = 0; r < 4; ++r) {
                    int row = m_base + q4 * 4 + r;       // global M = b*L + l
                    int col = c_base + ct * 16 + ln;     // d
                    int bb = row >> 12, l = row & 4095;
                    vtb[(size_t)bb * (DD * LL) + (size_t)col * LL + l] = f2b(acc[ct][r]);
                }
        }
    }
}

// ---------------------------------------------------------------------------
// Kernel 2: causal ReLU attention, MFMA flash-style.
// 512 blocks (2 per CU): block handles ONE 32-row q-tile t of batch b.
// Index map pairs long+short tiles onto the same CU slot: blocks 2c,2c+1 get
// tiles p and 127-p -> 129 k-tile units per pair.
// Per k-tile (32 keys):
//   K-frags + V-frags issued back-to-back at iteration top (V lands during S)
//   S = Q Kt (two independent 4-MFMA chains)
//   P = relu(mask(S))/max(l,1) -> bf16 -> LDS (parity double-buffer)
//   one barrier
//   O += P V
// Register budget ~150 VGPR (aQ 32 + kf 32 + vf 32 + oacc 32 + misc): must
// NOT spill — round-3's kf double-buffer + unroll 2 spilled ~1 GB to scratch.
// ---------------------------------------------------------------------------
#define LSTRIDE 40   // LDS row stride in shorts (padded: 80B, 16B-aligned)

__global__ __launch_bounds__(256, 2) void attn_kernel(
    const u16* __restrict__ qb, const u16* __restrict__ kb,
    const u16* __restrict__ vtb, u16* __restrict__ ctxb)
{
    __shared__ u16 ps[2][32 * LSTRIDE];

    const int i = blockIdx.x;
    const int b = (i >> 1) & 3;
    const int p = i >> 3;
    const int t = (i & 1) ? p : 127 - p;

    const int w = threadIdx.x >> 6, lane = threadIdx.x & 63;
    const int q4 = lane >> 4, ln = lane & 15;
    const int wr = w >> 1, wc = w & 1;

    const u16* qB = qb + (size_t)b * LL * DD;
    const u16* kB = kb + (size_t)b * LL * DD;
    const u16* vB = vtb + (size_t)b * DD * LL;

    // Q A-fragments, resident: rows [32t + 16wr, +16)
    bf16x8 aQ[8];
    {
        const u16* q0 = qB + (size_t)(t * 32 + wr * 16 + ln) * DD;
        #pragma unroll
        for (int ks = 0; ks < 8; ++ks)
            aQ[ks] = *(const bf16x8*)(q0 + ks * 32 + q4 * 8);
    }

    f32x4 oacc[8];
    #pragma unroll
    for (int tt = 0; tt < 8; ++tt) oacc[tt] = f32x4{0.f, 0.f, 0.f, 0.f};

    float inv[4];
    #pragma unroll
    for (int r = 0; r < 4; ++r) {
        int row = t * 32 + wr * 16 + q4 * 4 + r;
        inv[r] = 1.0f / (float)(row > 1 ? row : 1);
    }

    const int rowl = wr * 16 + q4 * 4;
    const int coll = wc * 16 + ln;

    #pragma unroll 1
    for (int kt = 0; kt <= t; ++kt) {
        const int cur = kt & 1;

        // ---- K-frags for THIS kt (needed first, issued first) ----
        bf16x8 kf[8];
        {
            const u16* krow = kB + (size_t)(kt * 32 + wc * 16 + ln) * DD;
            #pragma unroll
            for (int ks = 0; ks < 8; ++ks)
                kf[ks] = *(const bf16x8*)(krow + ks * 32 + q4 * 8);
        }
        // ---- V-frags for THIS kt: in flight through the S phase ----
        bf16x8 vf[8];
        #pragma unroll
        for (int tt = 0; tt < 8; ++tt)
            vf[tt] = *(const bf16x8*)(vB + (size_t)(wc * 128 + tt * 16 + ln) * LL + kt * 32 + q4 * 8);

        // ---- S phase: two independent 4-MFMA chains ----
        f32x4 sa = f32x4{0.f, 0.f, 0.f, 0.f};
        f32x4 sb = f32x4{0.f, 0.f, 0.f, 0.f};
        #pragma unroll
        for (int ks = 0; ks < 4; ++ks) {
            sa = mfma16(aQ[2 * ks], kf[2 * ks], sa);
            sb = mfma16(aQ[2 * ks + 1], kf[2 * ks + 1], sb);
        }

        // ---- mask / relu / scale -> LDS (parity buffer) ----
        const bool diag = (kt == t);
        #pragma unroll
        for (int r = 0; r < 4; ++r) {
            float v = fmaxf(sa[r] + sb[r], 0.f) * inv[r];
            if (diag && (coll > rowl + r)) v = 0.f;
            ps[cur][(rowl + r) * LSTRIDE + coll] = f2b(v);
        }
        __syncthreads();

        // ---- PV phase ----
        bf16x8 ap = *(const bf16x8*)(&ps[cur][(wr * 16 + ln) * LSTRIDE + q4 * 8]);
        #pragma unroll
        for (int tt = 0; tt < 8; ++tt)
            oacc[tt] = mfma16(ap, vf[tt], oacc[tt]);
        // no second barrier: next iteration writes ps[cur^1]; ps[cur] is only
        // rewritten at kt+2, after the kt+1 barrier.
    }

    // ---- epilogue: store ctx (bf16) ----
    #pragma unroll
    for (int tt = 0; tt < 8; ++tt)
        #pragma unroll
        for (int r = 0; r < 4; ++r) {
            int row = t * 32 + wr * 16 + q4 * 4 + r;
            int col = wc * 128 + tt * 16 + ln;
            ctxb[((size_t)b * LL + row) * DD + col] = f2b(oacc[tt][r]);
        }
}

// ---------------------------------------------------------------------------
// Kernel 3: output projection via MFMA (ctx bf16 @ Wo^T), fp32 store.
// 512 blocks: (row-group of 64) x (col-half of 128).
// ---------------------------------------------------------------------------
__global__ __launch_bounds__(256, 2) void oproj_kernel(
    const u16* __restrict__ ctxb, const u16* __restrict__ wob,
    float* __restrict__ out)
{
    const int w = threadIdx.x >> 6, lane = threadIdx.x & 63;
    const int q4 = lane >> 4, ln = lane & 15;
    const int g = blockIdx.x >> 1, half = blockIdx.x & 1;
    const int m_base = g * 64 + w * 16;
    const int c_base = half * 128;

    bf16x8 a[8];
    const u16* crow = ctxb + (size_t)(m_base + ln) * DD;
    #pragma unroll
    for (int ks = 0; ks < 8; ++ks)
        a[ks] = *(const bf16x8*)(crow + ks * 32 + q4 * 8);

    f32x4 acc[8];
    #pragma unroll
    for (int ct = 0; ct < 8; ++ct) acc[ct] = f32x4{0.f, 0.f, 0.f, 0.f};
    #pragma unroll
    for (int ks = 0; ks < 8; ++ks) {
        #pragma unroll
        for (int ct = 0; ct < 8; ++ct) {
            bf16x8 bf = *(const bf16x8*)(wob + (size_t)(c_base + ct * 16 + ln) * DD + ks * 32 + q4 * 8);
            acc[ct] = mfma16(a[ks], bf, acc[ct]);
        }
    }
    #pragma unroll
    for (int ct = 0; ct < 8; ++ct)
        #pragma unroll
        for (int r = 0; r < 4; ++r) {
            int row = m_base + q4 * 4 + r;
            int col = c_base + ct * 16 + ln;
            out[(size_t)row * DD + col] = acc[ct][r];
        }
}

extern "C" void kernel_launch(void* const* d_in, const int* in_sizes, int n_in,
                              void* d_out, int out_size, void* d_ws, size_t ws_size,
                              hipStream_t stream)
{
    const float* x  = (const float*)d_in[0];
    const float* Wq = (const float*)d_in[1];
    const float* Wk = (const float*)d_in[2];
    const float* Wv = (const float*)d_in[3];
    const float* Wo = (const float*)d_in[4];
    float* out = (float*)d_out;

    const size_t nW = (size_t)DD * DD;        // 65536
    const size_t nX = (size_t)BB * LL * DD;   // 4,194,304

    u16* wqb  = (u16*)d_ws;
    u16* wkb  = wqb + nW;
    u16* wvb  = wkb + nW;
    u16* wob  = wvb + nW;
    u16* qb   = wob + nW;
    u16* kb   = qb + nX;
    u16* vtb  = kb + nX;        // transposed: [B][D][L]
    u16* ctxb = vtb + nX;       // total ~34 MB

    wconv_kernel<<<dim3(DD * DD / 256), dim3(256), 0, stream>>>(
        Wq, Wk, Wv, Wo, wqb, wkb, wvb, wob);
    qkv_kernel<<<dim3(2 * BB * LL / 64), dim3(256), 0, stream>>>(
        x, wqb, wkb, wvb, qb, kb, vtb);
    attn_kernel<<<dim3(512), dim3(256), 0, stream>>>(qb, kb, vtb, ctxb);
    oproj_kernel<<<dim3(2 * BB * LL / 64), dim3(256), 0, stream>>>(ctxb, wob, out);
}

// Round 5
// 410.348 us; speedup vs baseline: 2.0383x; 1.3423x over previous
//
#include <hip/hip_runtime.h>

#define BB 4
#define LL 4096
#define DD 256

typedef short bf16x8 __attribute__((ext_vector_type(8)));
typedef float f32x4 __attribute__((ext_vector_type(4)));
typedef unsigned short u16;

__device__ inline u16 f2b(float f) {
    union { float f; unsigned u; } v; v.f = f;
    unsigned r = (v.u + 0x7fffu + ((v.u >> 16) & 1u)) >> 16;  // RNE
    return (u16)r;
}

__device__ inline f32x4 mfma16(bf16x8 a, bf16x8 b, f32x4 c) {
    return __builtin_amdgcn_mfma_f32_16x16x32_bf16(a, b, c, 0, 0, 0);
}

// ===========================================================================
// Fragment-order layouts (all 1KB chunks; within a chunk, lane l owns bytes
// [l*16, l*16+16) — so one global_load_dwordx4 per wave is fully coalesced).
//   A/B-frag content per lane (16x16x32): M/N-row = lane&15, 8 consecutive
//   K-elems starting at (lane>>4)*8.
// wfrag  (per matrix): chunk(ct,ks)        = W[ct*16+ln][ks*32+q4*8 ..+8]
// qfrag / kfrag:       chunk(bigT,h,ks)    = Q[bigT*32+h*16+ln][ks*32+q4*8..]
//                        (bigT = global 32-row token tile, h = 16-row half)
// vfrag:               chunk(bigT,h,tt)    = V[bigT*32+q4*8+j][h*128+tt*16+ln]
// ctxfrag:             chunk(m16,ks)       = ctx[m16*16+ln][ks*32+q4*8 ..+8]
// ===========================================================================

// ---------------------------------------------------------------------------
// Kernel 0: weights fp32 -> bf16 in B-frag order. 128 blocks x 256.
// wave handles one chunk: id = blk*4 + w -> (mat, ct, ks).
// ---------------------------------------------------------------------------
__global__ __launch_bounds__(256) void wconv_kernel(
    const float* __restrict__ Wq, const float* __restrict__ Wk,
    const float* __restrict__ Wv, const float* __restrict__ Wo,
    u16* __restrict__ wf)   // 4 matrices x 65536 u16
{
    const int w = threadIdx.x >> 6, lane = threadIdx.x & 63;
    const int q4 = lane >> 4, ln = lane & 15;
    const int id = blockIdx.x * 4 + w;          // 0..511
    const int mat = id >> 7, rem = id & 127, ct = rem >> 3, ks = rem & 7;
    const float* W = (mat == 0) ? Wq : (mat == 1) ? Wk : (mat == 2) ? Wv : Wo;
    const float* src = W + (size_t)(ct * 16 + ln) * DD + ks * 32 + q4 * 8;
    float4 f0 = ((const float4*)src)[0], f1 = ((const float4*)src)[1];
    bf16x8 t;
    t[0] = (short)f2b(f0.x); t[1] = (short)f2b(f0.y);
    t[2] = (short)f2b(f0.z); t[3] = (short)f2b(f0.w);
    t[4] = (short)f2b(f1.x); t[5] = (short)f2b(f1.y);
    t[6] = (short)f2b(f1.z); t[7] = (short)f2b(f1.w);
    *(bf16x8*)(wf + (size_t)mat * 65536 + (ct * 8 + ks) * 512 + lane * 8) = t;
}

// ---------------------------------------------------------------------------
// Kernel 1: QKV projection. 512 blocks: g (64 tokens) x half (128 dims).
// NT GEMM with frag-order W (coalesced B loads). Outputs written in
// frag order via LDS transpose:
//   Q,K : LDS [token64][136]  (A-orientation),  2-way bank (free)
//   V   : LDS [dim128][72]    (B-of-V^T),       2-way bank (free)
// ---------------------------------------------------------------------------
__global__ __launch_bounds__(256, 2) void qkv_kernel(
    const float* __restrict__ x, const u16* __restrict__ wf,
    u16* __restrict__ qf, u16* __restrict__ kf_, u16* __restrict__ vf_)
{
    __shared__ u16 lt[9216];   // max(64*136, 128*72)

    const int w = threadIdx.x >> 6, lane = threadIdx.x & 63;
    const int q4 = lane >> 4, ln = lane & 15;
    const int g = blockIdx.x >> 1, half = blockIdx.x & 1;
    const int m0 = g * 64;

    // A-frags: x rows (fp32 -> bf16), resident for all three matmuls
    bf16x8 a[8];
    {
        const float* xrow = x + (size_t)(m0 + w * 16 + ln) * DD;
        #pragma unroll
        for (int ks = 0; ks < 8; ++ks) {
            const float4* p = (const float4*)(xrow + ks * 32 + q4 * 8);
            float4 f0 = p[0], f1 = p[1];
            bf16x8 t;
            t[0] = (short)f2b(f0.x); t[1] = (short)f2b(f0.y);
            t[2] = (short)f2b(f0.z); t[3] = (short)f2b(f0.w);
            t[4] = (short)f2b(f1.x); t[5] = (short)f2b(f1.y);
            t[6] = (short)f2b(f1.z); t[7] = (short)f2b(f1.w);
            a[ks] = t;
        }
    }

    #pragma unroll 1
    for (int wi = 0; wi < 3; ++wi) {
        const u16* W = wf + (size_t)wi * 65536;
        f32x4 acc[8];
        #pragma unroll
        for (int cl = 0; cl < 8; ++cl) acc[cl] = f32x4{0.f, 0.f, 0.f, 0.f};
        #pragma unroll
        for (int ks = 0; ks < 8; ++ks) {
            #pragma unroll
            for (int cl = 0; cl < 8; ++cl) {
                bf16x8 bfr = *(const bf16x8*)(W + ((half * 8 + cl) * 8 + ks) * 512 + lane * 8);
                acc[cl] = mfma16(a[ks], bfr, acc[cl]);
            }
        }

        if (wi < 2) {
            // C-layout -> LDS [token64][136]
            #pragma unroll
            for (int cl = 0; cl < 8; ++cl)
                #pragma unroll
                for (int r = 0; r < 4; ++r)
                    lt[(w * 16 + q4 * 4 + r) * 136 + cl * 16 + ln] = f2b(acc[cl][r]);
            __syncthreads();
            // wave w -> (T_l = w>>1, h = w&1), 4 chunks (ksl)
            {
                const int T_l = w >> 1, h = w & 1;
                const int bigT = g * 2 + T_l;
                u16* dst = (wi == 0) ? qf : kf_;
                #pragma unroll
                for (int ksl = 0; ksl < 4; ++ksl) {
                    const int ks = half * 4 + ksl;
                    bf16x8 af = *(const bf16x8*)&lt[(T_l * 32 + h * 16 + ln) * 136 + ksl * 32 + q4 * 8];
                    *(bf16x8*)(dst + (size_t)((bigT * 2 + h) * 8 + ks) * 512 + lane * 8) = af;
                }
            }
            __syncthreads();
        } else {
            // V: C-layout -> LDS [dim128][72] (transposed orientation)
            #pragma unroll
            for (int cl = 0; cl < 8; ++cl)
                #pragma unroll
                for (int r = 0; r < 4; ++r)
                    lt[(cl * 16 + ln) * 72 + w * 16 + q4 * 4 + r] = f2b(acc[cl][r]);
            __syncthreads();
            {
                const int T_l = w >> 1;
                const int bigT = g * 2 + T_l;
                #pragma unroll
                for (int ttl = 0; ttl < 4; ++ttl) {
                    const int tt = (w & 1) * 4 + ttl;
                    bf16x8 af = *(const bf16x8*)&lt[(tt * 16 + ln) * 72 + T_l * 32 + q4 * 8];
                    *(bf16x8*)(vf_ + (size_t)((bigT * 2 + half) * 8 + tt) * 512 + lane * 8) = af;
                }
            }
        }
    }
}

// ---------------------------------------------------------------------------
// Kernel 2: causal ReLU attention. 512 blocks (2/CU, all co-resident).
// Block = one 32-row q-tile; blocks i and i+256 get tiles (127-ti) and ti so
// each CU slot pair sums to 129 k-tiles under round-robin dispatch.
// Inner loop: ALL global loads are coalesced dwordx4 from frag-order buffers.
//   S  = Q K^T   (8 MFMA, two independent chains)
//   P -> LDS (parity buffer, padded)  -> one barrier
//   O += P V     (8 MFMA)
// Epilogue: LDS transpose -> ctx in A-frag order (coalesced stores).
// ---------------------------------------------------------------------------
#define LSTRIDE 40   // ps row stride (u16): 80B, 16B-aligned, 2-way free

__global__ __launch_bounds__(256, 2) void attn_kernel(
    const u16* __restrict__ qf, const u16* __restrict__ kfr,
    const u16* __restrict__ vfr, u16* __restrict__ cf)
{
    __shared__ u16 ps[2][32 * LSTRIDE];
    __shared__ u16 et[32 * 264];

    const int slot = blockIdx.x & 255, round = blockIdx.x >> 8;
    const int b = slot & 3, ti = slot >> 2;
    const int t = round ? ti : 127 - ti;

    const int w = threadIdx.x >> 6, lane = threadIdx.x & 63;
    const int q4 = lane >> 4, ln = lane & 15;
    const int wr = w >> 1, wc = w & 1;
    const int bigTq = b * 128 + t;

    // Q A-frags (coalesced; wr-pair waves share chunks via L1)
    bf16x8 aQ[8];
    #pragma unroll
    for (int ks = 0; ks < 8; ++ks)
        aQ[ks] = *(const bf16x8*)(qf + (size_t)((bigTq * 2 + wr) * 8 + ks) * 512 + lane * 8);

    f32x4 oacc[8];
    #pragma unroll
    for (int tt = 0; tt < 8; ++tt) oacc[tt] = f32x4{0.f, 0.f, 0.f, 0.f};

    float inv[4];
    #pragma unroll
    for (int r = 0; r < 4; ++r) {
        int row = t * 32 + wr * 16 + q4 * 4 + r;
        inv[r] = 1.0f / (float)(row > 1 ? row : 1);
    }

    const int rowl = wr * 16 + q4 * 4;
    const int coll = wc * 16 + ln;

    #pragma unroll 1
    for (int kt = 0; kt <= t; ++kt) {
        const int cur = kt & 1;
        const size_t cbase = (size_t)((b * 128 + kt) * 2 + wc) * 8 * 512;

        // ---- coalesced frag loads: K (needed first), V (lands during S) ----
        bf16x8 kf[8];
        #pragma unroll
        for (int ks = 0; ks < 8; ++ks)
            kf[ks] = *(const bf16x8*)(kfr + cbase + ks * 512 + lane * 8);
        bf16x8 vf[8];
        #pragma unroll
        for (int tt = 0; tt < 8; ++tt)
            vf[tt] = *(const bf16x8*)(vfr + cbase + tt * 512 + lane * 8);

        // ---- S phase ----
        f32x4 sa = f32x4{0.f, 0.f, 0.f, 0.f};
        f32x4 sb = f32x4{0.f, 0.f, 0.f, 0.f};
        #pragma unroll
        for (int ks = 0; ks < 4; ++ks) {
            sa = mfma16(aQ[2 * ks], kf[2 * ks], sa);
            sb = mfma16(aQ[2 * ks + 1], kf[2 * ks + 1], sb);
        }

        // ---- mask / relu / scale -> ps (parity) ----
        const bool diag = (kt == t);
        #pragma unroll
        for (int r = 0; r < 4; ++r) {
            float v = fmaxf(sa[r] + sb[r], 0.f) * inv[r];
            if (diag && (coll > rowl + r)) v = 0.f;
            ps[cur][(rowl + r) * LSTRIDE + coll] = f2b(v);
        }
        __syncthreads();

        // ---- PV phase ----
        bf16x8 ap = *(const bf16x8*)(&ps[cur][(wr * 16 + ln) * LSTRIDE + q4 * 8]);
        #pragma unroll
        for (int tt = 0; tt < 8; ++tt)
            oacc[tt] = mfma16(ap, vf[tt], oacc[tt]);
    }

    // ---- epilogue: C-layout -> et [32 rows][264] -> ctxfrag (A-frag order)
    #pragma unroll
    for (int tt = 0; tt < 8; ++tt)
        #pragma unroll
        for (int r = 0; r < 4; ++r)
            et[(wr * 16 + q4 * 4 + r) * 264 + wc * 128 + tt * 16 + ln] = f2b(oacc[tt][r]);
    __syncthreads();
    {
        const int m16 = bigTq * 2 + wr;
        #pragma unroll
        for (int ksl = 0; ksl < 4; ++ksl) {
            const int ks = wc * 4 + ksl;
            bf16x8 af = *(const bf16x8*)&et[(wr * 16 + ln) * 264 + ks * 32 + q4 * 8];
            *(bf16x8*)(cf + (size_t)(m16 * 8 + ks) * 512 + lane * 8) = af;
        }
    }
}

// ---------------------------------------------------------------------------
// Kernel 3: output projection. 512 blocks: g (64 tokens) x half (128 dims).
// ctx A-frags + Wo B-frags both coalesced; fp32 out through LDS transpose
// for coalesced float4 stores.
// ---------------------------------------------------------------------------
__global__ __launch_bounds__(256, 2) void oproj_kernel(
    const u16* __restrict__ cf, const u16* __restrict__ wfo,
    float* __restrict__ out)
{
    __shared__ float ot[64 * 132];

    const int w = threadIdx.x >> 6, lane = threadIdx.x & 63;
    const int q4 = lane >> 4, ln = lane & 15;
    const int g = blockIdx.x >> 1, half = blockIdx.x & 1;
    const int m16 = g * 4 + w;

    bf16x8 a[8];
    #pragma unroll
    for (int ks = 0; ks < 8; ++ks)
        a[ks] = *(const bf16x8*)(cf + (size_t)(m16 * 8 + ks) * 512 + lane * 8);

    f32x4 acc[8];
    #pragma unroll
    for (int cl = 0; cl < 8; ++cl) acc[cl] = f32x4{0.f, 0.f, 0.f, 0.f};
    #pragma unroll
    for (int ks = 0; ks < 8; ++ks) {
        #pragma unroll
        for (int cl = 0; cl < 8; ++cl) {
            bf16x8 bfr = *(const bf16x8*)(wfo + ((half * 8 + cl) * 8 + ks) * 512 + lane * 8);
            acc[cl] = mfma16(a[ks], bfr, acc[cl]);
        }
    }

    #pragma unroll
    for (int cl = 0; cl < 8; ++cl)
        #pragma unroll
        for (int r = 0; r < 4; ++r)
            ot[(w * 16 + q4 * 4 + r) * 132 + cl * 16 + ln] = acc[cl][r];
    __syncthreads();

    #pragma unroll
    for (int it = 0; it < 8; ++it) {
        int idx = it * 256 + threadIdx.x;
        int tok = idx >> 5, d4 = idx & 31;
        float4 v = *(const float4*)&ot[tok * 132 + d4 * 4];
        *(float4*)(out + (size_t)(g * 64 + tok) * DD + half * 128 + d4 * 4) = v;
    }
}

extern "C" void kernel_launch(void* const* d_in, const int* in_sizes, int n_in,
                              void* d_out, int out_size, void* d_ws, size_t ws_size,
                              hipStream_t stream)
{
    const float* x  = (const float*)d_in[0];
    const float* Wq = (const float*)d_in[1];
    const float* Wk = (const float*)d_in[2];
    const float* Wv = (const float*)d_in[3];
    const float* Wo = (const float*)d_in[4];
    float* out = (float*)d_out;

    const size_t nW = (size_t)DD * DD;        // 65536
    const size_t nX = (size_t)BB * LL * DD;   // 4,194,304

    u16* wf  = (u16*)d_ws;                    // 4 matrices, frag order
    u16* qfr = wf + 4 * nW;
    u16* kfr = qfr + nX;
    u16* vfr = kfr + nX;
    u16* cfr = vfr + nX;                      // total ~34 MB

    wconv_kernel<<<dim3(128), dim3(256), 0, stream>>>(Wq, Wk, Wv, Wo, wf);
    qkv_kernel<<<dim3(512), dim3(256), 0, stream>>>(x, wf, qfr, kfr, vfr);
    attn_kernel<<<dim3(512), dim3(256), 0, stream>>>(qfr, kfr, vfr, cfr);
    oproj_kernel<<<dim3(512), dim3(256), 0, stream>>>(cfr, wf + 3 * nW, out);
}

// Round 6
// 308.791 us; speedup vs baseline: 2.7087x; 1.3289x over previous
//
#include <hip/hip_runtime.h>

#define BB 4
#define LL 4096
#define DD 256

typedef short bf16x8 __attribute__((ext_vector_type(8)));
typedef short bf16x4 __attribute__((ext_vector_type(4)));
typedef float f32x4 __attribute__((ext_vector_type(4)));
typedef unsigned short u16;

__device__ inline u16 f2b(float f) {
    union { float f; unsigned u; } v; v.f = f;
    unsigned r = (v.u + 0x7fffu + ((v.u >> 16) & 1u)) >> 16;  // RNE
    return (u16)r;
}

__device__ inline f32x4 mfma32(bf16x8 a, bf16x8 b, f32x4 c) {
    return __builtin_amdgcn_mfma_f32_16x16x32_bf16(a, b, c, 0, 0, 0);
}
__device__ inline f32x4 mfma16(bf16x4 a, bf16x4 b, f32x4 c) {
    return __builtin_amdgcn_mfma_f32_16x16x16bf16_1k(a, b, c, 0, 0, 0);
}

// ===========================================================================
// Layouts (chunks are wave-loads: lane l owns bytes [l*16, l*16+16)):
// wfrag (per matrix): chunk(ct,ks)      = W[ct*16+ln][ks*32+q4*8 ..+8]
// qfrag/kfrag:        chunk(bigT,h,ks)  = Q[bigT*32+h*16+ln][ks*32+q4*8..+8]
// vfrag (K=16 A-of-V^T, both halves packed): chunk(kt32,dt), lane l=16q4+ln:
//        elems 0-3 = V[kt32*32     +q4*4+j][dt*16+ln]   (kh=0)
//        elems 4-7 = V[kt32*32+16  +q4*4+j][dt*16+ln]   (kh=1)
// cfrag:              chunk(m16,ks)     = ctx[m16*16+ln][ks*32+q4*8 ..+8]
// partials: part[(T*2+h)*16+dt][lane][reg] fp32, O^T-tile C-layout
// ===========================================================================

// ---------------------------------------------------------------------------
// Kernel 0: weights fp32 -> bf16 in B-frag order.
// ---------------------------------------------------------------------------
__global__ __launch_bounds__(256) void wconv_kernel(
    const float* __restrict__ Wq, const float* __restrict__ Wk,
    const float* __restrict__ Wv, const float* __restrict__ Wo,
    u16* __restrict__ wf)
{
    const int w = threadIdx.x >> 6, lane = threadIdx.x & 63;
    const int q4 = lane >> 4, ln = lane & 15;
    const int id = blockIdx.x * 4 + w;          // 0..511
    const int mat = id >> 7, rem = id & 127, ct = rem >> 3, ks = rem & 7;
    const float* W = (mat == 0) ? Wq : (mat == 1) ? Wk : (mat == 2) ? Wv : Wo;
    const float* src = W + (size_t)(ct * 16 + ln) * DD + ks * 32 + q4 * 8;
    float4 f0 = ((const float4*)src)[0], f1 = ((const float4*)src)[1];
    bf16x8 t;
    t[0] = (short)f2b(f0.x); t[1] = (short)f2b(f0.y);
    t[2] = (short)f2b(f0.z); t[3] = (short)f2b(f0.w);
    t[4] = (short)f2b(f1.x); t[5] = (short)f2b(f1.y);
    t[6] = (short)f2b(f1.z); t[7] = (short)f2b(f1.w);
    *(bf16x8*)(wf + (size_t)mat * 65536 + (ct * 8 + ks) * 512 + lane * 8) = t;
}

// ---------------------------------------------------------------------------
// Kernel 1: QKV projection. 512 blocks: g (64 tokens) x half (128 dims).
// Q,K -> frag order via LDS transpose; V -> K=16 A-of-V^T packed chunks.
// ---------------------------------------------------------------------------
__global__ __launch_bounds__(256, 2) void qkv_kernel(
    const float* __restrict__ x, const u16* __restrict__ wf,
    u16* __restrict__ qf, u16* __restrict__ kf_, u16* __restrict__ vf_)
{
    __shared__ u16 lt[9216];   // max(64*136, 128*72)

    const int w = threadIdx.x >> 6, lane = threadIdx.x & 63;
    const int q4 = lane >> 4, ln = lane & 15;
    const int g = blockIdx.x >> 1, half = blockIdx.x & 1;
    const int m0 = g * 64;

    bf16x8 a[8];
    {
        const float* xrow = x + (size_t)(m0 + w * 16 + ln) * DD;
        #pragma unroll
        for (int ks = 0; ks < 8; ++ks) {
            const float4* p = (const float4*)(xrow + ks * 32 + q4 * 8);
            float4 f0 = p[0], f1 = p[1];
            bf16x8 t;
            t[0] = (short)f2b(f0.x); t[1] = (short)f2b(f0.y);
            t[2] = (short)f2b(f0.z); t[3] = (short)f2b(f0.w);
            t[4] = (short)f2b(f1.x); t[5] = (short)f2b(f1.y);
            t[6] = (short)f2b(f1.z); t[7] = (short)f2b(f1.w);
            a[ks] = t;
        }
    }

    #pragma unroll 1
    for (int wi = 0; wi < 3; ++wi) {
        const u16* W = wf + (size_t)wi * 65536;
        f32x4 acc[8];
        #pragma unroll
        for (int cl = 0; cl < 8; ++cl) acc[cl] = f32x4{0.f, 0.f, 0.f, 0.f};
        #pragma unroll
        for (int ks = 0; ks < 8; ++ks) {
            #pragma unroll
            for (int cl = 0; cl < 8; ++cl) {
                bf16x8 bfr = *(const bf16x8*)(W + ((half * 8 + cl) * 8 + ks) * 512 + lane * 8);
                acc[cl] = mfma32(a[ks], bfr, acc[cl]);
            }
        }

        if (wi < 2) {
            #pragma unroll
            for (int cl = 0; cl < 8; ++cl)
                #pragma unroll
                for (int r = 0; r < 4; ++r)
                    lt[(w * 16 + q4 * 4 + r) * 136 + cl * 16 + ln] = f2b(acc[cl][r]);
            __syncthreads();
            {
                const int T_l = w >> 1, h = w & 1;
                const int bigT = g * 2 + T_l;
                u16* dst = (wi == 0) ? qf : kf_;
                #pragma unroll
                for (int ksl = 0; ksl < 4; ++ksl) {
                    const int ks = half * 4 + ksl;
                    bf16x8 af = *(const bf16x8*)&lt[(T_l * 32 + h * 16 + ln) * 136 + ksl * 32 + q4 * 8];
                    *(bf16x8*)(dst + (size_t)((bigT * 2 + h) * 8 + ks) * 512 + lane * 8) = af;
                }
            }
            __syncthreads();
        } else {
            // V: C-layout -> LDS [dim_local 128][token 72]
            #pragma unroll
            for (int cl = 0; cl < 8; ++cl)
                #pragma unroll
                for (int r = 0; r < 4; ++r)
                    lt[(cl * 16 + ln) * 72 + w * 16 + q4 * 4 + r] = f2b(acc[cl][r]);
            __syncthreads();
            {
                const int kt32_l = w & 1;               // 32-key tile within g
                const int kt32g = g * 2 + kt32_l;
                const int tok0 = kt32_l * 32 + q4 * 4;
                #pragma unroll
                for (int i = 0; i < 4; ++i) {
                    const int dt_l = (w >> 1) * 4 + i;  // local d-tile [0,8)
                    const int dtg = half * 8 + dt_l;
                    const int dim_l = dt_l * 16 + ln;
                    bf16x4 lo = *(const bf16x4*)&lt[dim_l * 72 + tok0];
                    bf16x4 hi = *(const bf16x4*)&lt[dim_l * 72 + tok0 + 16];
                    bf16x8 t;
                    t[0] = lo[0]; t[1] = lo[1]; t[2] = lo[2]; t[3] = lo[3];
                    t[4] = hi[0]; t[5] = hi[1]; t[6] = hi[2]; t[7] = hi[3];
                    *(bf16x8*)(vf_ + (size_t)(kt32g * 16 + dtg) * 512 + lane * 8) = t;
                }
            }
        }
    }
}

// ---------------------------------------------------------------------------
// Kernel 2: causal ReLU attention — barrier-free, LDS-free, per-wave tiles.
// 512 blocks x 4 waves; wave = (batch=waveid, q-tile t (16 rows), k-half).
// Block p,r: t = r ? p : 255-p; h = r. Blocks c and c+256 are complementary
// in size -> balanced per CU. Per 32-key tile:
//   S^T = K Q^T  (2 x 8 mfma 16x16x32; keys=M, queries=N)
//   P^T = relu(mask(S^T)) * 1/max(q,1)  -> pack bf16 IN REGISTER
//        (C/D layout == 16x16x16 B-frag layout, lane-identical: no LDS!)
//   O^T += V^T P^T  (32 x mfma 16x16x16, K=16)
// Partial O^T (fp32, C-layout) -> workspace; reduce_kernel combines halves.
// ---------------------------------------------------------------------------
__global__ __launch_bounds__(256, 2) void attn_kernel(
    const u16* __restrict__ qf, const u16* __restrict__ kfr,
    const u16* __restrict__ vfr, float* __restrict__ part)
{
    const int p = blockIdx.x & 255, r = blockIdx.x >> 8;
    const int t = r ? p : 255 - p;
    const int w = threadIdx.x >> 6, lane = threadIdx.x & 63;
    const int q4 = lane >> 4, ln = lane & 15;
    const int b = w;
    const int T = b * 256 + t;
    const int nk = (t >> 1) + 1, nk0 = (nk + 1) >> 1;
    const int k0 = r ? nk0 : 0, k1 = r ? nk : nk0;
    const int qg = t * 16 + ln;                       // global query row (col)
    const float inv = 1.0f / (float)(qg > 1 ? qg : 1);

    // resident Q B-frags (8 chunks)
    bf16x8 qB[8];
    {
        const u16* qb = qf + (size_t)(((b * 128 + (t >> 1)) * 2 + (t & 1)) * 8) * 512 + lane * 8;
        #pragma unroll
        for (int ks = 0; ks < 8; ++ks)
            qB[ks] = *(const bf16x8*)(qb + ks * 512);
    }

    f32x4 oacc[16];
    #pragma unroll
    for (int dt = 0; dt < 16; ++dt) oacc[dt] = f32x4{0.f, 0.f, 0.f, 0.f};

    #pragma unroll 1
    for (int kt = k0; kt < k1; ++kt) {
        // K frags (kh=0,1), coalesced dwordx4
        const u16* kc = kfr + (size_t)((b * 128 + kt) * 16) * 512 + lane * 8;
        bf16x8 kf0[8], kf1[8];
        #pragma unroll
        for (int ks = 0; ks < 8; ++ks) {
            kf0[ks] = *(const bf16x8*)(kc + ks * 512);
            kf1[ks] = *(const bf16x8*)(kc + (8 + ks) * 512);
        }
        // V frags (16 d-tiles, both kh halves packed per chunk)
        const u16* vc = vfr + (size_t)((b * 128 + kt) * 16) * 512 + lane * 8;
        bf16x8 vf[16];
        #pragma unroll
        for (int dt = 0; dt < 16; ++dt)
            vf[dt] = *(const bf16x8*)(vc + dt * 512);

        // S^T = K Q^T : two 16(key)x16(query) C-tiles
        f32x4 s0 = f32x4{0.f, 0.f, 0.f, 0.f};
        f32x4 s1 = f32x4{0.f, 0.f, 0.f, 0.f};
        #pragma unroll
        for (int ks = 0; ks < 8; ++ks) {
            s0 = mfma32(kf0[ks], qB[ks], s0);
            s1 = mfma32(kf1[ks], qB[ks], s1);
        }

        // mask (key>query -> 0), relu, scale; pack to B-frags in-register
        const int kb0 = kt * 32 + q4 * 4 - qg;        // key - query, kh=0, reg 0
        bf16x4 p0, p1;
        #pragma unroll
        for (int rr = 0; rr < 4; ++rr) {
            float v0 = (kb0 + rr > 0) ? 0.f : fmaxf(s0[rr], 0.f) * inv;
            float v1 = (kb0 + 16 + rr > 0) ? 0.f : fmaxf(s1[rr], 0.f) * inv;
            p0[rr] = (short)f2b(v0);
            p1[rr] = (short)f2b(v1);
        }

        // O^T += V^T P^T
        #pragma unroll
        for (int dt = 0; dt < 16; ++dt) {
            bf16x4 a0 = __builtin_shufflevector(vf[dt], vf[dt], 0, 1, 2, 3);
            bf16x4 a1 = __builtin_shufflevector(vf[dt], vf[dt], 4, 5, 6, 7);
            oacc[dt] = mfma16(a0, p0, oacc[dt]);
            oacc[dt] = mfma16(a1, p1, oacc[dt]);
        }
    }

    // store fp32 partials (C-layout linear; always written, zero if no iters)
    float* pb = part + ((size_t)(T * 2 + r) * 16) * 256 + lane * 4;
    #pragma unroll
    for (int dt = 0; dt < 16; ++dt)
        *(f32x4*)(pb + dt * 256) = oacc[dt];
}

// ---------------------------------------------------------------------------
// Kernel 2b: reduce the two k-half partials -> ctx in A-frag order (cfrag).
// One wave per (T, ks) chunk; 2048 blocks x 4 waves.
// ---------------------------------------------------------------------------
__global__ __launch_bounds__(256) void reduce_kernel(
    const float* __restrict__ part, u16* __restrict__ cf)
{
    const int gid = blockIdx.x * 4 + (threadIdx.x >> 6);  // 0..8191
    const int lane = threadIdx.x & 63;
    const int q4 = lane >> 4, ln = lane & 15;
    const int T = gid >> 3, ks = gid & 7;
    const int dt = 2 * ks + (q4 >> 1);
    const int q4a = (q4 & 1) * 2;

    const float* b0 = part + ((size_t)(T * 2 + 0) * 16 + dt) * 256;
    const float* b1 = part + ((size_t)(T * 2 + 1) * 16 + dt) * 256;
    f32x4 a0 = *(const f32x4*)(b0 + (16 * q4a + ln) * 4);
    f32x4 c0 = *(const f32x4*)(b0 + (16 * (q4a + 1) + ln) * 4);
    f32x4 a1 = *(const f32x4*)(b1 + (16 * q4a + ln) * 4);
    f32x4 c1 = *(const f32x4*)(b1 + (16 * (q4a + 1) + ln) * 4);
    f32x4 sa = a0 + a1, sb = c0 + c1;

    bf16x8 t;
    #pragma unroll
    for (int j = 0; j < 4; ++j) {
        t[j] = (short)f2b(sa[j]);
        t[4 + j] = (short)f2b(sb[j]);
    }
    *(bf16x8*)(cf + (size_t)(T * 8 + ks) * 512 + lane * 8) = t;
}

// ---------------------------------------------------------------------------
// Kernel 3: output projection (ctx frag @ Wo frag), fp32 out via LDS.
// ---------------------------------------------------------------------------
__global__ __launch_bounds__(256, 2) void oproj_kernel(
    const u16* __restrict__ cf, const u16* __restrict__ wfo,
    float* __restrict__ out)
{
    __shared__ float ot[64 * 132];

    const int w = threadIdx.x >> 6, lane = threadIdx.x & 63;
    const int q4 = lane >> 4, ln = lane & 15;
    const int g = blockIdx.x >> 1, half = blockIdx.x & 1;
    const int m16 = g * 4 + w;

    bf16x8 a[8];
    #pragma unroll
    for (int ks = 0; ks < 8; ++ks)
        a[ks] = *(const bf16x8*)(cf + (size_t)(m16 * 8 + ks) * 512 + lane * 8);

    f32x4 acc[8];
    #pragma unroll
    for (int cl = 0; cl < 8; ++cl) acc[cl] = f32x4{0.f, 0.f, 0.f, 0.f};
    #pragma unroll
    for (int ks = 0; ks < 8; ++ks) {
        #pragma unroll
        for (int cl = 0; cl < 8; ++cl) {
            bf16x8 bfr = *(const bf16x8*)(wfo + ((half * 8 + cl) * 8 + ks) * 512 + lane * 8);
            acc[cl] = mfma32(a[ks], bfr, acc[cl]);
        }
    }

    #pragma unroll
    for (int cl = 0; cl < 8; ++cl)
        #pragma unroll
        for (int r = 0; r < 4; ++r)
            ot[(w * 16 + q4 * 4 + r) * 132 + cl * 16 + ln] = acc[cl][r];
    __syncthreads();

    #pragma unroll
    for (int it = 0; it < 8; ++it) {
        int idx = it * 256 + threadIdx.x;
        int tok = idx >> 5, d4 = idx & 31;
        float4 v = *(const float4*)&ot[tok * 132 + d4 * 4];
        *(float4*)(out + (size_t)(g * 64 + tok) * DD + half * 128 + d4 * 4) = v;
    }
}

extern "C" void kernel_launch(void* const* d_in, const int* in_sizes, int n_in,
                              void* d_out, int out_size, void* d_ws, size_t ws_size,
                              hipStream_t stream)
{
    const float* x  = (const float*)d_in[0];
    const float* Wq = (const float*)d_in[1];
    const float* Wk = (const float*)d_in[2];
    const float* Wv = (const float*)d_in[3];
    const float* Wo = (const float*)d_in[4];
    float* out = (float*)d_out;

    const size_t nW = (size_t)DD * DD;        // 65536
    const size_t nX = (size_t)BB * LL * DD;   // 4,194,304

    u16* wf   = (u16*)d_ws;                   // 4 matrices, frag order (512 KB)
    u16* qfr  = wf + 4 * nW;                  // 8 MB
    u16* kfr  = qfr + nX;                     // 8 MB
    u16* vfr  = kfr + nX;                     // 8 MB
    float* part = (float*)(vfr + nX);         // 1024*2*16*256 fp32 = 33.5 MB
    u16* cfr  = qfr;                          // reuse Q buffer after attn

    wconv_kernel<<<dim3(128), dim3(256), 0, stream>>>(Wq, Wk, Wv, Wo, wf);
    qkv_kernel<<<dim3(512), dim3(256), 0, stream>>>(x, wf, qfr, kfr, vfr);
    attn_kernel<<<dim3(512), dim3(256), 0, stream>>>(qfr, kfr, vfr, part);
    reduce_kernel<<<dim3(2048), dim3(256), 0, stream>>>(part, cfr);
    oproj_kernel<<<dim3(512), dim3(256), 0, stream>>>(cfr, wf + 3 * nW, out);
}

// Round 7
// 211.882 us; speedup vs baseline: 3.9475x; 1.4574x over previous
//
#include <hip/hip_runtime.h>

#define BB 4
#define LL 4096
#define DD 256

typedef short bf16x8 __attribute__((ext_vector_type(8)));
typedef short bf16x4 __attribute__((ext_vector_type(4)));
typedef float f32x4 __attribute__((ext_vector_type(4)));
typedef unsigned short u16;

__device__ inline u16 f2b(float f) {
    union { float f; unsigned u; } v; v.f = f;
    unsigned r = (v.u + 0x7fffu + ((v.u >> 16) & 1u)) >> 16;  // RNE
    return (u16)r;
}

__device__ inline f32x4 mfma32(bf16x8 a, bf16x8 b, f32x4 c) {
    return __builtin_amdgcn_mfma_f32_16x16x32_bf16(a, b, c, 0, 0, 0);
}
__device__ inline f32x4 mfma16(bf16x4 a, bf16x4 b, f32x4 c) {
    return __builtin_amdgcn_mfma_f32_16x16x16bf16_1k(a, b, c, 0, 0, 0);
}

// async global->LDS: per-lane 16B, dest = wave-uniform base + lane*16
__device__ inline void gl_lds(const u16* g, u16* l) {
    __builtin_amdgcn_global_load_lds(
        (const __attribute__((address_space(1))) void*)g,
        (__attribute__((address_space(3))) void*)l, 16, 0, 0);
}

// ===========================================================================
// Layouts (chunks are wave-loads: lane l owns bytes [l*16, l*16+16)):
// wfrag (per matrix): chunk(ct,ks)      = W[ct*16+ln][ks*32+q4*8 ..+8]
// qfrag/kfrag:        chunk(bigT,h,ks)  = Q[bigT*32+h*16+ln][ks*32+q4*8..+8]
// vfrag (K=16 A-of-V^T, both halves packed): chunk(kt32,dt), lane l=16q4+ln:
//        elems 0-3 = V[kt32*32     +q4*4+j][dt*16+ln]   (kh=0)
//        elems 4-7 = V[kt32*32+16  +q4*4+j][dt*16+ln]   (kh=1)
// cfrag:              chunk(m16,ks)     = ctx[m16*16+ln][ks*32+q4*8 ..+8]
// partials: part[(T*2+h)*16+dt][lane][reg] fp32, O^T-tile C-layout
// ===========================================================================

__global__ __launch_bounds__(256) void wconv_kernel(
    const float* __restrict__ Wq, const float* __restrict__ Wk,
    const float* __restrict__ Wv, const float* __restrict__ Wo,
    u16* __restrict__ wf)
{
    const int w = threadIdx.x >> 6, lane = threadIdx.x & 63;
    const int q4 = lane >> 4, ln = lane & 15;
    const int id = blockIdx.x * 4 + w;          // 0..511
    const int mat = id >> 7, rem = id & 127, ct = rem >> 3, ks = rem & 7;
    const float* W = (mat == 0) ? Wq : (mat == 1) ? Wk : (mat == 2) ? Wv : Wo;
    const float* src = W + (size_t)(ct * 16 + ln) * DD + ks * 32 + q4 * 8;
    float4 f0 = ((const float4*)src)[0], f1 = ((const float4*)src)[1];
    bf16x8 t;
    t[0] = (short)f2b(f0.x); t[1] = (short)f2b(f0.y);
    t[2] = (short)f2b(f0.z); t[3] = (short)f2b(f0.w);
    t[4] = (short)f2b(f1.x); t[5] = (short)f2b(f1.y);
    t[6] = (short)f2b(f1.z); t[7] = (short)f2b(f1.w);
    *(bf16x8*)(wf + (size_t)mat * 65536 + (ct * 8 + ks) * 512 + lane * 8) = t;
}

// ---------------------------------------------------------------------------
// Kernel 1: QKV projection. 512 blocks: g (64 tokens) x half (128 dims).
// ---------------------------------------------------------------------------
__global__ __launch_bounds__(256, 2) void qkv_kernel(
    const float* __restrict__ x, const u16* __restrict__ wf,
    u16* __restrict__ qf, u16* __restrict__ kf_, u16* __restrict__ vf_)
{
    __shared__ u16 lt[9216];   // max(64*136, 128*72)

    const int w = threadIdx.x >> 6, lane = threadIdx.x & 63;
    const int q4 = lane >> 4, ln = lane & 15;
    const int g = blockIdx.x >> 1, half = blockIdx.x & 1;
    const int m0 = g * 64;

    bf16x8 a[8];
    {
        const float* xrow = x + (size_t)(m0 + w * 16 + ln) * DD;
        #pragma unroll
        for (int ks = 0; ks < 8; ++ks) {
            const float4* p = (const float4*)(xrow + ks * 32 + q4 * 8);
            float4 f0 = p[0], f1 = p[1];
            bf16x8 t;
            t[0] = (short)f2b(f0.x); t[1] = (short)f2b(f0.y);
            t[2] = (short)f2b(f0.z); t[3] = (short)f2b(f0.w);
            t[4] = (short)f2b(f1.x); t[5] = (short)f2b(f1.y);
            t[6] = (short)f2b(f1.z); t[7] = (short)f2b(f1.w);
            a[ks] = t;
        }
    }

    #pragma unroll 1
    for (int wi = 0; wi < 3; ++wi) {
        const u16* W = wf + (size_t)wi * 65536;
        f32x4 acc[8];
        #pragma unroll
        for (int cl = 0; cl < 8; ++cl) acc[cl] = f32x4{0.f, 0.f, 0.f, 0.f};
        #pragma unroll
        for (int ks = 0; ks < 8; ++ks) {
            #pragma unroll
            for (int cl = 0; cl < 8; ++cl) {
                bf16x8 bfr = *(const bf16x8*)(W + ((half * 8 + cl) * 8 + ks) * 512 + lane * 8);
                acc[cl] = mfma32(a[ks], bfr, acc[cl]);
            }
        }

        if (wi < 2) {
            #pragma unroll
            for (int cl = 0; cl < 8; ++cl)
                #pragma unroll
                for (int r = 0; r < 4; ++r)
                    lt[(w * 16 + q4 * 4 + r) * 136 + cl * 16 + ln] = f2b(acc[cl][r]);
            __syncthreads();
            {
                const int T_l = w >> 1, h = w & 1;
                const int bigT = g * 2 + T_l;
                u16* dst = (wi == 0) ? qf : kf_;
                #pragma unroll
                for (int ksl = 0; ksl < 4; ++ksl) {
                    const int ks = half * 4 + ksl;
                    bf16x8 af = *(const bf16x8*)&lt[(T_l * 32 + h * 16 + ln) * 136 + ksl * 32 + q4 * 8];
                    *(bf16x8*)(dst + (size_t)((bigT * 2 + h) * 8 + ks) * 512 + lane * 8) = af;
                }
            }
            __syncthreads();
        } else {
            #pragma unroll
            for (int cl = 0; cl < 8; ++cl)
                #pragma unroll
                for (int r = 0; r < 4; ++r)
                    lt[(cl * 16 + ln) * 72 + w * 16 + q4 * 4 + r] = f2b(acc[cl][r]);
            __syncthreads();
            {
                const int kt32_l = w & 1;
                const int kt32g = g * 2 + kt32_l;
                const int tok0 = kt32_l * 32 + q4 * 4;
                #pragma unroll
                for (int i = 0; i < 4; ++i) {
                    const int dt_l = (w >> 1) * 4 + i;
                    const int dtg = half * 8 + dt_l;
                    const int dim_l = dt_l * 16 + ln;
                    bf16x4 lo = *(const bf16x4*)&lt[dim_l * 72 + tok0];
                    bf16x4 hi = *(const bf16x4*)&lt[dim_l * 72 + tok0 + 16];
                    bf16x8 t;
                    t[0] = lo[0]; t[1] = lo[1]; t[2] = lo[2]; t[3] = lo[3];
                    t[4] = hi[0]; t[5] = hi[1]; t[6] = hi[2]; t[7] = hi[3];
                    *(bf16x8*)(vf_ + (size_t)(kt32g * 16 + dtg) * 512 + lane * 8) = t;
                }
            }
        }
    }
}

// ---------------------------------------------------------------------------
// Kernel 2: causal ReLU attention — block-cooperative K/V via LDS.
// 512 blocks x 4 waves. Block = (batch b, 64-query group g, k-half h).
//   b = (i>>1)&3  -> batch pinned to XCD pair {2b,2b+1} (XCD = i&7 heuristic)
//   s = ((i>>3)&31)<<1 | (i&1);  r = i>>8;  g = r ? s : 63-s;  h = r
//   -> CU slot gets (64-s) + (s+1) = 65 iterations: balanced.
// Wave w owns 16-q tile tile16 = g*4+w. Per 32-key tile kt:
//   [barrier] [prefetch kt+1 K/V chunks -> LDS buf^1 via global_load_lds]
//   S^T = K Q^T (LDS K-frags), P^T packed in-register (C==B-frag trick),
//   O^T += V^T P^T (LDS V-frags). One barrier/iter; loads fly under compute.
// h=0: kt in [0, g+1);  h=1: kt in [g+1, 2g+2). Partials -> reduce_kernel.
// ---------------------------------------------------------------------------
__global__ __launch_bounds__(256, 2) void attn_kernel(
    const u16* __restrict__ qf, const u16* __restrict__ kfr,
    const u16* __restrict__ vfr, float* __restrict__ part)
{
    __shared__ u16 buf[2][32][512];   // [parity][chunk][1KB chunk] = 64 KB

    const int i = blockIdx.x;
    const int b = (i >> 1) & 3;
    const int s = (((i >> 3) & 31) << 1) | (i & 1);
    const int r = i >> 8;
    const int g = r ? s : 63 - s;
    const int k0 = r ? (g + 1) : 0;
    const int k1 = r ? (2 * g + 2) : (g + 1);

    const int w = threadIdx.x >> 6, lane = threadIdx.x & 63;
    const int q4 = lane >> 4, ln = lane & 15;
    const int tile16 = g * 4 + w;
    const int T = b * 256 + tile16;
    const int qg = tile16 * 16 + ln;
    const float inv = 1.0f / (float)(qg > 1 ? qg : 1);

    // resident Q B-frags
    bf16x8 qB[8];
    {
        const u16* qb = qf + (size_t)(((b * 128 + (tile16 >> 1)) * 2 + (tile16 & 1)) * 8) * 512 + lane * 8;
        #pragma unroll
        for (int ks = 0; ks < 8; ++ks)
            qB[ks] = *(const bf16x8*)(qb + ks * 512);
    }

    f32x4 oacc[16];
    #pragma unroll
    for (int dt = 0; dt < 16; ++dt) oacc[dt] = f32x4{0.f, 0.f, 0.f, 0.f};

    // prologue: stage kt=k0 into buf[k0&1] (wave w covers chunks w*8..w*8+7)
    {
        const size_t cb = (size_t)((b * 128 + k0) * 16) * 512;
        #pragma unroll
        for (int j = 0; j < 8; ++j) {
            const int c = w * 8 + j;
            const u16* gsrc = ((c < 16) ? (kfr + cb + c * 512)
                                        : (vfr + cb + (c - 16) * 512)) + lane * 8;
            gl_lds(gsrc, &buf[k0 & 1][c][0]);
        }
    }

    #pragma unroll 1
    for (int kt = k0; kt < k1; ++kt) {
        const int cur = kt & 1;
        __syncthreads();   // drains this wave's loads; all waves' chunks in LDS

        if (kt + 1 < k1) {
            const size_t cb = (size_t)((b * 128 + kt + 1) * 16) * 512;
            #pragma unroll
            for (int j = 0; j < 8; ++j) {
                const int c = w * 8 + j;
                const u16* gsrc = ((c < 16) ? (kfr + cb + c * 512)
                                            : (vfr + cb + (c - 16) * 512)) + lane * 8;
                gl_lds(gsrc, &buf[cur ^ 1][c][0]);
            }
        }

        // ---- S^T = K Q^T ----
        f32x4 s0 = f32x4{0.f, 0.f, 0.f, 0.f};
        f32x4 s1 = f32x4{0.f, 0.f, 0.f, 0.f};
        #pragma unroll
        for (int ks = 0; ks < 8; ++ks) {
            bf16x8 kf0 = *(const bf16x8*)&buf[cur][ks][lane * 8];
            bf16x8 kf1 = *(const bf16x8*)&buf[cur][8 + ks][lane * 8];
            s0 = mfma32(kf0, qB[ks], s0);
            s1 = mfma32(kf1, qB[ks], s1);
        }

        // ---- mask/relu/scale, pack P^T to B-frags in-register ----
        const int kb0 = kt * 32 + q4 * 4 - qg;
        bf16x4 p0, p1;
        #pragma unroll
        for (int rr = 0; rr < 4; ++rr) {
            float v0 = (kb0 + rr > 0) ? 0.f : fmaxf(s0[rr], 0.f) * inv;
            float v1 = (kb0 + 16 + rr > 0) ? 0.f : fmaxf(s1[rr], 0.f) * inv;
            p0[rr] = (short)f2b(v0);
            p1[rr] = (short)f2b(v1);
        }

        // ---- O^T += V^T P^T ----
        #pragma unroll
        for (int dt = 0; dt < 16; ++dt) {
            bf16x8 vv = *(const bf16x8*)&buf[cur][16 + dt][lane * 8];
            bf16x4 a0 = __builtin_shufflevector(vv, vv, 0, 1, 2, 3);
            bf16x4 a1 = __builtin_shufflevector(vv, vv, 4, 5, 6, 7);
            oacc[dt] = mfma16(a0, p0, oacc[dt]);
            oacc[dt] = mfma16(a1, p1, oacc[dt]);
        }
    }

    // store fp32 partials (C-layout linear)
    float* pb = part + ((size_t)(T * 2 + r) * 16) * 256 + lane * 4;
    #pragma unroll
    for (int dt = 0; dt < 16; ++dt)
        *(f32x4*)(pb + dt * 256) = oacc[dt];
}

// ---------------------------------------------------------------------------
// Kernel 2b: reduce the two k-half partials -> ctx in A-frag order.
// ---------------------------------------------------------------------------
__global__ __launch_bounds__(256) void reduce_kernel(
    const float* __restrict__ part, u16* __restrict__ cf)
{
    const int gid = blockIdx.x * 4 + (threadIdx.x >> 6);  // 0..8191
    const int lane = threadIdx.x & 63;
    const int q4 = lane >> 4, ln = lane & 15;
    const int T = gid >> 3, ks = gid & 7;
    const int dt = 2 * ks + (q4 >> 1);
    const int q4a = (q4 & 1) * 2;

    const float* b0 = part + ((size_t)(T * 2 + 0) * 16 + dt) * 256;
    const float* b1 = part + ((size_t)(T * 2 + 1) * 16 + dt) * 256;
    f32x4 a0 = *(const f32x4*)(b0 + (16 * q4a + ln) * 4);
    f32x4 c0 = *(const f32x4*)(b0 + (16 * (q4a + 1) + ln) * 4);
    f32x4 a1 = *(const f32x4*)(b1 + (16 * q4a + ln) * 4);
    f32x4 c1 = *(const f32x4*)(b1 + (16 * (q4a + 1) + ln) * 4);
    f32x4 sa = a0 + a1, sb = c0 + c1;

    bf16x8 t;
    #pragma unroll
    for (int j = 0; j < 4; ++j) {
        t[j] = (short)f2b(sa[j]);
        t[4 + j] = (short)f2b(sb[j]);
    }
    *(bf16x8*)(cf + (size_t)(T * 8 + ks) * 512 + lane * 8) = t;
}

// ---------------------------------------------------------------------------
// Kernel 3: output projection (ctx frag @ Wo frag), fp32 out via LDS.
// ---------------------------------------------------------------------------
__global__ __launch_bounds__(256, 2) void oproj_kernel(
    const u16* __restrict__ cf, const u16* __restrict__ wfo,
    float* __restrict__ out)
{
    __shared__ float ot[64 * 132];

    const int w = threadIdx.x >> 6, lane = threadIdx.x & 63;
    const int q4 = lane >> 4, ln = lane & 15;
    const int g = blockIdx.x >> 1, half = blockIdx.x & 1;
    const int m16 = g * 4 + w;

    bf16x8 a[8];
    #pragma unroll
    for (int ks = 0; ks < 8; ++ks)
        a[ks] = *(const bf16x8*)(cf + (size_t)(m16 * 8 + ks) * 512 + lane * 8);

    f32x4 acc[8];
    #pragma unroll
    for (int cl = 0; cl < 8; ++cl) acc[cl] = f32x4{0.f, 0.f, 0.f, 0.f};
    #pragma unroll
    for (int ks = 0; ks < 8; ++ks) {
        #pragma unroll
        for (int cl = 0; cl < 8; ++cl) {
            bf16x8 bfr = *(const bf16x8*)(wfo + ((half * 8 + cl) * 8 + ks) * 512 + lane * 8);
            acc[cl] = mfma32(a[ks], bfr, acc[cl]);
        }
    }

    #pragma unroll
    for (int cl = 0; cl < 8; ++cl)
        #pragma unroll
        for (int r = 0; r < 4; ++r)
            ot[(w * 16 + q4 * 4 + r) * 132 + cl * 16 + ln] = acc[cl][r];
    __syncthreads();

    #pragma unroll
    for (int it = 0; it < 8; ++it) {
        int idx = it * 256 + threadIdx.x;
        int tok = idx >> 5, d4 = idx & 31;
        float4 v = *(const float4*)&ot[tok * 132 + d4 * 4];
        *(float4*)(out + (size_t)(g * 64 + tok) * DD + half * 128 + d4 * 4) = v;
    }
}

extern "C" void kernel_launch(void* const* d_in, const int* in_sizes, int n_in,
                              void* d_out, int out_size, void* d_ws, size_t ws_size,
                              hipStream_t stream)
{
    const float* x  = (const float*)d_in[0];
    const float* Wq = (const float*)d_in[1];
    const float* Wk = (const float*)d_in[2];
    const float* Wv = (const float*)d_in[3];
    const float* Wo = (const float*)d_in[4];
    float* out = (float*)d_out;

    const size_t nW = (size_t)DD * DD;        // 65536
    const size_t nX = (size_t)BB * LL * DD;   // 4,194,304

    u16* wf   = (u16*)d_ws;                   // 4 matrices, frag order (512 KB)
    u16* qfr  = wf + 4 * nW;                  // 8 MB
    u16* kfr  = qfr + nX;                     // 8 MB
    u16* vfr  = kfr + nX;                     // 8 MB
    float* part = (float*)(vfr + nX);         // 33.5 MB
    u16* cfr  = qfr;                          // reuse Q buffer after attn

    wconv_kernel<<<dim3(128), dim3(256), 0, stream>>>(Wq, Wk, Wv, Wo, wf);
    qkv_kernel<<<dim3(512), dim3(256), 0, stream>>>(x, wf, qfr, kfr, vfr);
    attn_kernel<<<dim3(512), dim3(256), 0, stream>>>(qfr, kfr, vfr, part);
    reduce_kernel<<<dim3(2048), dim3(256), 0, stream>>>(part, cfr);
    oproj_kernel<<<dim3(512), dim3(256), 0, stream>>>(cfr, wf + 3 * nW, out);
}

// Round 8
// 209.982 us; speedup vs baseline: 3.9832x; 1.0090x over previous
//
#include <hip/hip_runtime.h>

#define BB 4
#define LL 4096
#define DD 256

typedef short bf16x8 __attribute__((ext_vector_type(8)));
typedef short bf16x4 __attribute__((ext_vector_type(4)));
typedef float f32x4 __attribute__((ext_vector_type(4)));
typedef unsigned short u16;

__device__ inline u16 f2b(float f) {
    union { float f; unsigned u; } v; v.f = f;
    unsigned r = (v.u + 0x7fffu + ((v.u >> 16) & 1u)) >> 16;  // RNE
    return (u16)r;
}

__device__ inline f32x4 mfma32(bf16x8 a, bf16x8 b, f32x4 c) {
    return __builtin_amdgcn_mfma_f32_16x16x32_bf16(a, b, c, 0, 0, 0);
}
__device__ inline f32x4 mfma16(bf16x4 a, bf16x4 b, f32x4 c) {
    return __builtin_amdgcn_mfma_f32_16x16x16bf16_1k(a, b, c, 0, 0, 0);
}

// async global->LDS: per-lane 16B, dest = wave-uniform base + lane*16
__device__ inline void gl_lds(const u16* g, u16* l) {
    __builtin_amdgcn_global_load_lds(
        (const __attribute__((address_space(1))) void*)g,
        (__attribute__((address_space(3))) void*)l, 16, 0, 0);
}

// ===========================================================================
// Layouts (1KB chunks unless noted; lane l owns bytes [l*16, l*16+16)):
// wfrag (Wq,Wk,Wv):   chunk(ct,ks)      = W[ct*16+ln][ks*32+q4*8 ..+8]
// wo16  (Wo, K=16 A-frag, 512B chunks): chunk(ct,kk), lane owns 8B:
//                       Wo[ct*16+ln][kk*16+q4*4 ..+4]
// qfrag/kfrag:        chunk(bigT,h,ks)  = Q[bigT*32+h*16+ln][ks*32+q4*8..+8]
// vfrag (K=16 A-of-V^T, both kh halves packed): chunk(kt32,dt):
//        elems 0-3 = V[kt32*32    +q4*4+j][dt*16+ln]
//        elems 4-7 = V[kt32*32+16 +q4*4+j][dt*16+ln]
// partials: part[(T*2+h)*16+dt][lane*4] fp32 — O^T tile in C-layout
//           (C-layout == 16x16x16 B-frag layout: consumed directly by oproj)
// ===========================================================================

// ---------------------------------------------------------------------------
// Kernel 0: weight conversion. ids 0..383: Wq/Wk/Wv -> B-frag order.
// ids 384..511: Wo -> K=16 A-frag order (wo16), 2 chunks per id.
// ---------------------------------------------------------------------------
__global__ __launch_bounds__(256) void wconv_kernel(
    const float* __restrict__ Wq, const float* __restrict__ Wk,
    const float* __restrict__ Wv, const float* __restrict__ Wo,
    u16* __restrict__ wf, u16* __restrict__ wo16)
{
    const int w = threadIdx.x >> 6, lane = threadIdx.x & 63;
    const int q4 = lane >> 4, ln = lane & 15;
    const int id = blockIdx.x * 4 + w;          // 0..511
    const int mat = id >> 7, rem = id & 127, ct = rem >> 3, ks = rem & 7;
    if (mat < 3) {
        const float* W = (mat == 0) ? Wq : (mat == 1) ? Wk : Wv;
        const float* src = W + (size_t)(ct * 16 + ln) * DD + ks * 32 + q4 * 8;
        float4 f0 = ((const float4*)src)[0], f1 = ((const float4*)src)[1];
        bf16x8 t;
        t[0] = (short)f2b(f0.x); t[1] = (short)f2b(f0.y);
        t[2] = (short)f2b(f0.z); t[3] = (short)f2b(f0.w);
        t[4] = (short)f2b(f1.x); t[5] = (short)f2b(f1.y);
        t[6] = (short)f2b(f1.z); t[7] = (short)f2b(f1.w);
        *(bf16x8*)(wf + (size_t)mat * 65536 + (ct * 8 + ks) * 512 + lane * 8) = t;
    } else {
        // Wo -> wo16: kk = 2ks and 2ks+1
        const float* src = Wo + (size_t)(ct * 16 + ln) * DD + ks * 32 + q4 * 4;
        float4 f0 = *(const float4*)src;          // kk = 2ks
        float4 f1 = *(const float4*)(src + 16);   // kk = 2ks+1
        bf16x4 t0, t1;
        t0[0] = (short)f2b(f0.x); t0[1] = (short)f2b(f0.y);
        t0[2] = (short)f2b(f0.z); t0[3] = (short)f2b(f0.w);
        t1[0] = (short)f2b(f1.x); t1[1] = (short)f2b(f1.y);
        t1[2] = (short)f2b(f1.z); t1[3] = (short)f2b(f1.w);
        *(bf16x4*)(wo16 + (size_t)(ct * 16 + 2 * ks) * 256 + lane * 4) = t0;
        *(bf16x4*)(wo16 + (size_t)(ct * 16 + 2 * ks + 1) * 256 + lane * 4) = t1;
    }
}

// ---------------------------------------------------------------------------
// Kernel 1: QKV projection, single pass. 512 blocks: g (64 tok) x half (128).
// Three independent accumulator sets interleaved in one ks-loop: 3x the
// load/MFMA ILP of the serial per-matrix version. acc 96 + a 32 VGPRs.
// ---------------------------------------------------------------------------
__global__ __launch_bounds__(256, 2) void qkv_kernel(
    const float* __restrict__ x, const u16* __restrict__ wf,
    u16* __restrict__ qf, u16* __restrict__ kf_, u16* __restrict__ vf_)
{
    __shared__ u16 lt[9216];   // max(64*136, 128*72)

    const int w = threadIdx.x >> 6, lane = threadIdx.x & 63;
    const int q4 = lane >> 4, ln = lane & 15;
    const int g = blockIdx.x >> 1, half = blockIdx.x & 1;
    const int m0 = g * 64;

    bf16x8 a[8];
    {
        const float* xrow = x + (size_t)(m0 + w * 16 + ln) * DD;
        #pragma unroll
        for (int ks = 0; ks < 8; ++ks) {
            const float4* p = (const float4*)(xrow + ks * 32 + q4 * 8);
            float4 f0 = p[0], f1 = p[1];
            bf16x8 t;
            t[0] = (short)f2b(f0.x); t[1] = (short)f2b(f0.y);
            t[2] = (short)f2b(f0.z); t[3] = (short)f2b(f0.w);
            t[4] = (short)f2b(f1.x); t[5] = (short)f2b(f1.y);
            t[6] = (short)f2b(f1.z); t[7] = (short)f2b(f1.w);
            a[ks] = t;
        }
    }

    f32x4 acc0[8], acc1[8], acc2[8];
    #pragma unroll
    for (int cl = 0; cl < 8; ++cl) {
        acc0[cl] = f32x4{0.f, 0.f, 0.f, 0.f};
        acc1[cl] = f32x4{0.f, 0.f, 0.f, 0.f};
        acc2[cl] = f32x4{0.f, 0.f, 0.f, 0.f};
    }

    #pragma unroll
    for (int ks = 0; ks < 8; ++ks) {
        #pragma unroll
        for (int cl = 0; cl < 8; ++cl) {
            const size_t off = ((size_t)(half * 8 + cl) * 8 + ks) * 512 + lane * 8;
            bf16x8 b0 = *(const bf16x8*)(wf + off);
            bf16x8 b1 = *(const bf16x8*)(wf + 65536 + off);
            bf16x8 b2 = *(const bf16x8*)(wf + 131072 + off);
            acc0[cl] = mfma32(a[ks], b0, acc0[cl]);
            acc1[cl] = mfma32(a[ks], b1, acc1[cl]);
            acc2[cl] = mfma32(a[ks], b2, acc2[cl]);
        }
    }

    // ---- epilogue: Q ----
    #pragma unroll
    for (int cl = 0; cl < 8; ++cl)
        #pragma unroll
        for (int r = 0; r < 4; ++r)
            lt[(w * 16 + q4 * 4 + r) * 136 + cl * 16 + ln] = f2b(acc0[cl][r]);
    __syncthreads();
    {
        const int T_l = w >> 1, h = w & 1;
        const int bigT = g * 2 + T_l;
        #pragma unroll
        for (int ksl = 0; ksl < 4; ++ksl) {
            const int ks = half * 4 + ksl;
            bf16x8 af = *(const bf16x8*)&lt[(T_l * 32 + h * 16 + ln) * 136 + ksl * 32 + q4 * 8];
            *(bf16x8*)(qf + (size_t)((bigT * 2 + h) * 8 + ks) * 512 + lane * 8) = af;
        }
    }
    __syncthreads();

    // ---- epilogue: K ----
    #pragma unroll
    for (int cl = 0; cl < 8; ++cl)
        #pragma unroll
        for (int r = 0; r < 4; ++r)
            lt[(w * 16 + q4 * 4 + r) * 136 + cl * 16 + ln] = f2b(acc1[cl][r]);
    __syncthreads();
    {
        const int T_l = w >> 1, h = w & 1;
        const int bigT = g * 2 + T_l;
        #pragma unroll
        for (int ksl = 0; ksl < 4; ++ksl) {
            const int ks = half * 4 + ksl;
            bf16x8 af = *(const bf16x8*)&lt[(T_l * 32 + h * 16 + ln) * 136 + ksl * 32 + q4 * 8];
            *(bf16x8*)(kf_ + (size_t)((bigT * 2 + h) * 8 + ks) * 512 + lane * 8) = af;
        }
    }
    __syncthreads();

    // ---- epilogue: V (transposed orientation) ----
    #pragma unroll
    for (int cl = 0; cl < 8; ++cl)
        #pragma unroll
        for (int r = 0; r < 4; ++r)
            lt[(cl * 16 + ln) * 72 + w * 16 + q4 * 4 + r] = f2b(acc2[cl][r]);
    __syncthreads();
    {
        const int kt32_l = w & 1;
        const int kt32g = g * 2 + kt32_l;
        const int tok0 = kt32_l * 32 + q4 * 4;
        #pragma unroll
        for (int i = 0; i < 4; ++i) {
            const int dt_l = (w >> 1) * 4 + i;
            const int dtg = half * 8 + dt_l;
            const int dim_l = dt_l * 16 + ln;
            bf16x4 lo = *(const bf16x4*)&lt[dim_l * 72 + tok0];
            bf16x4 hi = *(const bf16x4*)&lt[dim_l * 72 + tok0 + 16];
            bf16x8 t;
            t[0] = lo[0]; t[1] = lo[1]; t[2] = lo[2]; t[3] = lo[3];
            t[4] = hi[0]; t[5] = hi[1]; t[6] = hi[2]; t[7] = hi[3];
            *(bf16x8*)(vf_ + (size_t)(kt32g * 16 + dtg) * 512 + lane * 8) = t;
        }
    }
}

// ---------------------------------------------------------------------------
// Kernel 2: causal ReLU attention — unchanged from round 7 (87 µs, FETCH
// 27 MB ≈ ideal, MfmaUtil 22%). Block-cooperative K/V via LDS dbuf +
// global_load_lds; in-register P^T (C==B-frag); batch pinned to XCD pair.
// ---------------------------------------------------------------------------
__global__ __launch_bounds__(256, 2) void attn_kernel(
    const u16* __restrict__ qf, const u16* __restrict__ kfr,
    const u16* __restrict__ vfr, float* __restrict__ part)
{
    __shared__ u16 buf[2][32][512];   // 64 KB

    const int i = blockIdx.x;
    const int b = (i >> 1) & 3;
    const int s = (((i >> 3) & 31) << 1) | (i & 1);
    const int r = i >> 8;
    const int g = r ? s : 63 - s;
    const int k0 = r ? (g + 1) : 0;
    const int k1 = r ? (2 * g + 2) : (g + 1);

    const int w = threadIdx.x >> 6, lane = threadIdx.x & 63;
    const int q4 = lane >> 4, ln = lane & 15;
    const int tile16 = g * 4 + w;
    const int T = b * 256 + tile16;
    const int qg = tile16 * 16 + ln;
    const float inv = 1.0f / (float)(qg > 1 ? qg : 1);

    bf16x8 qB[8];
    {
        const u16* qb = qf + (size_t)(((b * 128 + (tile16 >> 1)) * 2 + (tile16 & 1)) * 8) * 512 + lane * 8;
        #pragma unroll
        for (int ks = 0; ks < 8; ++ks)
            qB[ks] = *(const bf16x8*)(qb + ks * 512);
    }

    f32x4 oacc[16];
    #pragma unroll
    for (int dt = 0; dt < 16; ++dt) oacc[dt] = f32x4{0.f, 0.f, 0.f, 0.f};

    {
        const size_t cb = (size_t)((b * 128 + k0) * 16) * 512;
        #pragma unroll
        for (int j = 0; j < 8; ++j) {
            const int c = w * 8 + j;
            const u16* gsrc = ((c < 16) ? (kfr + cb + c * 512)
                                        : (vfr + cb + (c - 16) * 512)) + lane * 8;
            gl_lds(gsrc, &buf[k0 & 1][c][0]);
        }
    }

    #pragma unroll 1
    for (int kt = k0; kt < k1; ++kt) {
        const int cur = kt & 1;
        __syncthreads();

        if (kt + 1 < k1) {
            const size_t cb = (size_t)((b * 128 + kt + 1) * 16) * 512;
            #pragma unroll
            for (int j = 0; j < 8; ++j) {
                const int c = w * 8 + j;
                const u16* gsrc = ((c < 16) ? (kfr + cb + c * 512)
                                            : (vfr + cb + (c - 16) * 512)) + lane * 8;
                gl_lds(gsrc, &buf[cur ^ 1][c][0]);
            }
        }

        f32x4 s0 = f32x4{0.f, 0.f, 0.f, 0.f};
        f32x4 s1 = f32x4{0.f, 0.f, 0.f, 0.f};
        #pragma unroll
        for (int ks = 0; ks < 8; ++ks) {
            bf16x8 kf0 = *(const bf16x8*)&buf[cur][ks][lane * 8];
            bf16x8 kf1 = *(const bf16x8*)&buf[cur][8 + ks][lane * 8];
            s0 = mfma32(kf0, qB[ks], s0);
            s1 = mfma32(kf1, qB[ks], s1);
        }

        const int kb0 = kt * 32 + q4 * 4 - qg;
        bf16x4 p0, p1;
        #pragma unroll
        for (int rr = 0; rr < 4; ++rr) {
            float v0 = (kb0 + rr > 0) ? 0.f : fmaxf(s0[rr], 0.f) * inv;
            float v1 = (kb0 + 16 + rr > 0) ? 0.f : fmaxf(s1[rr], 0.f) * inv;
            p0[rr] = (short)f2b(v0);
            p1[rr] = (short)f2b(v1);
        }

        #pragma unroll
        for (int dt = 0; dt < 16; ++dt) {
            bf16x8 vv = *(const bf16x8*)&buf[cur][16 + dt][lane * 8];
            bf16x4 a0 = __builtin_shufflevector(vv, vv, 0, 1, 2, 3);
            bf16x4 a1 = __builtin_shufflevector(vv, vv, 4, 5, 6, 7);
            oacc[dt] = mfma16(a0, p0, oacc[dt]);
            oacc[dt] = mfma16(a1, p1, oacc[dt]);
        }
    }

    float* pb = part + ((size_t)(T * 2 + r) * 16) * 256 + lane * 4;
    #pragma unroll
    for (int dt = 0; dt < 16; ++dt)
        *(f32x4*)(pb + dt * 256) = oacc[dt];
}

// ---------------------------------------------------------------------------
// Kernel 3: fused reduce + output projection. 512 blocks x 4 waves; block =
// 32 tokens (2 tok-tiles), all 256 out-dims. Computes out^T = Wo ctx^T:
//   Phase A: sum the two k-half partials (C-layout) -> pack bf16 -> LDS;
//            C-layout IS the 16x16x16 B-frag layout (no transpose needed).
//   Phase B: wave w: d-tiles [4w,4w+4): acc += mfma16(Wo_A(ct,dt), cb[tokt][dt])
//   Store: out^T C-tile -> out[tok][d]; q4-groups cover full 64B lines.
// ---------------------------------------------------------------------------
__global__ __launch_bounds__(256, 2) void oproj_kernel(
    const float* __restrict__ part, const u16* __restrict__ wo16,
    float* __restrict__ out)
{
    __shared__ u16 cb[2 * 16 * 256];   // [tokt][dt][lane*4] = 16 KB

    const int w = threadIdx.x >> 6, lane = threadIdx.x & 63;
    const int q4 = lane >> 4, ln = lane & 15;
    const int g = blockIdx.x;          // 32-token group, 0..511

    // Phase A: 32 chunks; wave w handles 8
    #pragma unroll
    for (int j = 0; j < 8; ++j) {
        const int idx = w * 8 + j;
        const int tokt = idx >> 4, dt = idx & 15;
        const int T = g * 2 + tokt;
        const float* p0 = part + ((size_t)(T * 2 + 0) * 16 + dt) * 256 + lane * 4;
        const float* p1 = part + ((size_t)(T * 2 + 1) * 16 + dt) * 256 + lane * 4;
        f32x4 s = *(const f32x4*)p0 + *(const f32x4*)p1;
        bf16x4 t;
        t[0] = (short)f2b(s[0]); t[1] = (short)f2b(s[1]);
        t[2] = (short)f2b(s[2]); t[3] = (short)f2b(s[3]);
        *(bf16x4*)&cb[(tokt * 16 + dt) * 256 + lane * 4] = t;
    }
    __syncthreads();

    // Phase B: wave w -> d-tiles [w*4, w*4+4)
    #pragma unroll
    for (int c4 = 0; c4 < 4; ++c4) {
        const int ct = w * 4 + c4;
        f32x4 acc0 = f32x4{0.f, 0.f, 0.f, 0.f};
        f32x4 acc1 = f32x4{0.f, 0.f, 0.f, 0.f};
        #pragma unroll
        for (int dt = 0; dt < 16; ++dt) {
            bf16x4 A = *(const bf16x4*)(wo16 + (size_t)(ct * 16 + dt) * 256 + lane * 4);
            bf16x4 B0 = *(const bf16x4*)&cb[(0 * 16 + dt) * 256 + lane * 4];
            bf16x4 B1 = *(const bf16x4*)&cb[(1 * 16 + dt) * 256 + lane * 4];
            acc0 = mfma16(A, B0, acc0);
            acc1 = mfma16(A, B1, acc1);
        }
        // store out^T C-tiles: lane col = token, rows = d
        float* o0 = out + (size_t)(g * 32 + 0 * 16 + ln) * DD + ct * 16 + q4 * 4;
        float* o1 = out + (size_t)(g * 32 + 1 * 16 + ln) * DD + ct * 16 + q4 * 4;
        *(f32x4*)o0 = acc0;
        *(f32x4*)o1 = acc1;
    }
}

extern "C" void kernel_launch(void* const* d_in, const int* in_sizes, int n_in,
                              void* d_out, int out_size, void* d_ws, size_t ws_size,
                              hipStream_t stream)
{
    const float* x  = (const float*)d_in[0];
    const float* Wq = (const float*)d_in[1];
    const float* Wk = (const float*)d_in[2];
    const float* Wv = (const float*)d_in[3];
    const float* Wo = (const float*)d_in[4];
    float* out = (float*)d_out;

    const size_t nW = (size_t)DD * DD;        // 65536
    const size_t nX = (size_t)BB * LL * DD;   // 4,194,304

    u16* wf   = (u16*)d_ws;                   // Wq,Wk,Wv B-frag order (384 KB)
    u16* wo16 = wf + 3 * nW;                  // Wo K=16 A-frag order (128 KB)
    u16* qfr  = wf + 4 * nW;                  // 8 MB
    u16* kfr  = qfr + nX;                     // 8 MB
    u16* vfr  = kfr + nX;                     // 8 MB
    float* part = (float*)(vfr + nX);         // 33.5 MB

    wconv_kernel<<<dim3(128), dim3(256), 0, stream>>>(Wq, Wk, Wv, Wo, wf, wo16);
    qkv_kernel<<<dim3(512), dim3(256), 0, stream>>>(x, wf, qfr, kfr, vfr);
    attn_kernel<<<dim3(512), dim3(256), 0, stream>>>(qfr, kfr, vfr, part);
    oproj_kernel<<<dim3(512), dim3(256), 0, stream>>>(part, wo16, out);
}

// Round 9
// 190.686 us; speedup vs baseline: 4.3863x; 1.1012x over previous
//
#include <hip/hip_runtime.h>

#define BB 4
#define LL 4096
#define DD 256

typedef short bf16x8 __attribute__((ext_vector_type(8)));
typedef short bf16x4 __attribute__((ext_vector_type(4)));
typedef float f32x4 __attribute__((ext_vector_type(4)));
typedef unsigned short u16;

__device__ inline u16 f2b(float f) {
    union { float f; unsigned u; } v; v.f = f;
    unsigned r = (v.u + 0x7fffu + ((v.u >> 16) & 1u)) >> 16;  // RNE
    return (u16)r;
}
__device__ inline float b2f(short s) {
    union { unsigned u; float f; } v; v.u = ((unsigned)(unsigned short)s) << 16;
    return v.f;
}

__device__ inline f32x4 mfma32(bf16x8 a, bf16x8 b, f32x4 c) {
    return __builtin_amdgcn_mfma_f32_16x16x32_bf16(a, b, c, 0, 0, 0);
}
__device__ inline f32x4 mfma16(bf16x4 a, bf16x4 b, f32x4 c) {
    return __builtin_amdgcn_mfma_f32_16x16x16bf16_1k(a, b, c, 0, 0, 0);
}

__device__ inline void gl_lds(const u16* g, u16* l) {
    __builtin_amdgcn_global_load_lds(
        (const __attribute__((address_space(1))) void*)g,
        (__attribute__((address_space(3))) void*)l, 16, 0, 0);
}

// ===========================================================================
// Layouts: see prior rounds. New: part = bf16 partials with 5 slots/tile:
//   part[((T*5 + slot)*16 + dt)*256 + lane*4], slot = segment - j0(g),
//   j0(g) = (2*(g*g+g)+1)/65.  Segment j covers flattened units
//   [floor(65j/2), floor(65(j+1)/2)) of U(g)=g*g+g+kt (per batch, 4160 units).
// ===========================================================================

__global__ __launch_bounds__(256) void wconv_kernel(
    const float* __restrict__ Wq, const float* __restrict__ Wk,
    const float* __restrict__ Wv, const float* __restrict__ Wo,
    u16* __restrict__ wf, u16* __restrict__ wo16)
{
    const int w = threadIdx.x >> 6, lane = threadIdx.x & 63;
    const int q4 = lane >> 4, ln = lane & 15;
    const int id = blockIdx.x * 4 + w;          // 0..511
    const int mat = id >> 7, rem = id & 127, ct = rem >> 3, ks = rem & 7;
    if (mat < 3) {
        const float* W = (mat == 0) ? Wq : (mat == 1) ? Wk : Wv;
        const float* src = W + (size_t)(ct * 16 + ln) * DD + ks * 32 + q4 * 8;
        float4 f0 = ((const float4*)src)[0], f1 = ((const float4*)src)[1];
        bf16x8 t;
        t[0] = (short)f2b(f0.x); t[1] = (short)f2b(f0.y);
        t[2] = (short)f2b(f0.z); t[3] = (short)f2b(f0.w);
        t[4] = (short)f2b(f1.x); t[5] = (short)f2b(f1.y);
        t[6] = (short)f2b(f1.z); t[7] = (short)f2b(f1.w);
        *(bf16x8*)(wf + (size_t)mat * 65536 + (ct * 8 + ks) * 512 + lane * 8) = t;
    } else {
        const float* src = Wo + (size_t)(ct * 16 + ln) * DD + ks * 32 + q4 * 4;
        float4 f0 = *(const float4*)src;
        float4 f1 = *(const float4*)(src + 16);
        bf16x4 t0, t1;
        t0[0] = (short)f2b(f0.x); t0[1] = (short)f2b(f0.y);
        t0[2] = (short)f2b(f0.z); t0[3] = (short)f2b(f0.w);
        t1[0] = (short)f2b(f1.x); t1[1] = (short)f2b(f1.y);
        t1[2] = (short)f2b(f1.z); t1[3] = (short)f2b(f1.w);
        *(bf16x4*)(wo16 + (size_t)(ct * 16 + 2 * ks) * 256 + lane * 4) = t0;
        *(bf16x4*)(wo16 + (size_t)(ct * 16 + 2 * ks + 1) * 256 + lane * 4) = t1;
    }
}

// ---------------------------------------------------------------------------
// Kernel 1: QKV projection, single pass (unchanged from round 8).
// ---------------------------------------------------------------------------
__global__ __launch_bounds__(256, 2) void qkv_kernel(
    const float* __restrict__ x, const u16* __restrict__ wf,
    u16* __restrict__ qf, u16* __restrict__ kf_, u16* __restrict__ vf_)
{
    __shared__ u16 lt[9216];

    const int w = threadIdx.x >> 6, lane = threadIdx.x & 63;
    const int q4 = lane >> 4, ln = lane & 15;
    const int g = blockIdx.x >> 1, half = blockIdx.x & 1;
    const int m0 = g * 64;

    bf16x8 a[8];
    {
        const float* xrow = x + (size_t)(m0 + w * 16 + ln) * DD;
        #pragma unroll
        for (int ks = 0; ks < 8; ++ks) {
            const float4* p = (const float4*)(xrow + ks * 32 + q4 * 8);
            float4 f0 = p[0], f1 = p[1];
            bf16x8 t;
            t[0] = (short)f2b(f0.x); t[1] = (short)f2b(f0.y);
            t[2] = (short)f2b(f0.z); t[3] = (short)f2b(f0.w);
            t[4] = (short)f2b(f1.x); t[5] = (short)f2b(f1.y);
            t[6] = (short)f2b(f1.z); t[7] = (short)f2b(f1.w);
            a[ks] = t;
        }
    }

    f32x4 acc0[8], acc1[8], acc2[8];
    #pragma unroll
    for (int cl = 0; cl < 8; ++cl) {
        acc0[cl] = f32x4{0.f, 0.f, 0.f, 0.f};
        acc1[cl] = f32x4{0.f, 0.f, 0.f, 0.f};
        acc2[cl] = f32x4{0.f, 0.f, 0.f, 0.f};
    }

    #pragma unroll
    for (int ks = 0; ks < 8; ++ks) {
        #pragma unroll
        for (int cl = 0; cl < 8; ++cl) {
            const size_t off = ((size_t)(half * 8 + cl) * 8 + ks) * 512 + lane * 8;
            bf16x8 b0 = *(const bf16x8*)(wf + off);
            bf16x8 b1 = *(const bf16x8*)(wf + 65536 + off);
            bf16x8 b2 = *(const bf16x8*)(wf + 131072 + off);
            acc0[cl] = mfma32(a[ks], b0, acc0[cl]);
            acc1[cl] = mfma32(a[ks], b1, acc1[cl]);
            acc2[cl] = mfma32(a[ks], b2, acc2[cl]);
        }
    }

    #pragma unroll
    for (int cl = 0; cl < 8; ++cl)
        #pragma unroll
        for (int r = 0; r < 4; ++r)
            lt[(w * 16 + q4 * 4 + r) * 136 + cl * 16 + ln] = f2b(acc0[cl][r]);
    __syncthreads();
    {
        const int T_l = w >> 1, h = w & 1;
        const int bigT = g * 2 + T_l;
        #pragma unroll
        for (int ksl = 0; ksl < 4; ++ksl) {
            const int ks = half * 4 + ksl;
            bf16x8 af = *(const bf16x8*)&lt[(T_l * 32 + h * 16 + ln) * 136 + ksl * 32 + q4 * 8];
            *(bf16x8*)(qf + (size_t)((bigT * 2 + h) * 8 + ks) * 512 + lane * 8) = af;
        }
    }
    __syncthreads();

    #pragma unroll
    for (int cl = 0; cl < 8; ++cl)
        #pragma unroll
        for (int r = 0; r < 4; ++r)
            lt[(w * 16 + q4 * 4 + r) * 136 + cl * 16 + ln] = f2b(acc1[cl][r]);
    __syncthreads();
    {
        const int T_l = w >> 1, h = w & 1;
        const int bigT = g * 2 + T_l;
        #pragma unroll
        for (int ksl = 0; ksl < 4; ++ksl) {
            const int ks = half * 4 + ksl;
            bf16x8 af = *(const bf16x8*)&lt[(T_l * 32 + h * 16 + ln) * 136 + ksl * 32 + q4 * 8];
            *(bf16x8*)(kf_ + (size_t)((bigT * 2 + h) * 8 + ks) * 512 + lane * 8) = af;
        }
    }
    __syncthreads();

    #pragma unroll
    for (int cl = 0; cl < 8; ++cl)
        #pragma unroll
        for (int r = 0; r < 4; ++r)
            lt[(cl * 16 + ln) * 72 + w * 16 + q4 * 4 + r] = f2b(acc2[cl][r]);
    __syncthreads();
    {
        const int kt32_l = w & 1;
        const int kt32g = g * 2 + kt32_l;
        const int tok0 = kt32_l * 32 + q4 * 4;
        #pragma unroll
        for (int i = 0; i < 4; ++i) {
            const int dt_l = (w >> 1) * 4 + i;
            const int dtg = half * 8 + dt_l;
            const int dim_l = dt_l * 16 + ln;
            bf16x4 lo = *(const bf16x4*)&lt[dim_l * 72 + tok0];
            bf16x4 hi = *(const bf16x4*)&lt[dim_l * 72 + tok0 + 16];
            bf16x8 t;
            t[0] = lo[0]; t[1] = lo[1]; t[2] = lo[2]; t[3] = lo[3];
            t[4] = hi[0]; t[5] = hi[1]; t[6] = hi[2]; t[7] = hi[3];
            *(bf16x8*)(vf_ + (size_t)(kt32g * 16 + dtg) * 512 + lane * 8) = t;
        }
    }
}

// ---------------------------------------------------------------------------
// Kernel 2: causal ReLU attention — EQUAL-WORK flattened partition.
// 512 blocks (2/CU): block = (batch b, segment j in [0,128)).
//   b = (i>>1)&3 (XCD-pinned);  j = ((i>>3)<<1)|(i&1).
// Segment j covers flattened units [65j/2, 65(j+1)/2) of the per-batch causal
// triangle, u = g*g + g + kt (g = 64-query group, kt = 32-key tile in
// [0, 2g+2)).  Every block: ~33 iterations — no long-block tail.
// At each g boundary: flush O^T partial (bf16) to slot (j - j0(g)), reload Q.
// K/V LDS double-buffer + global_load_lds prefetch crosses g boundaries.
// ---------------------------------------------------------------------------
__global__ __launch_bounds__(256, 2) void attn_kernel(
    const u16* __restrict__ qf, const u16* __restrict__ kfr,
    const u16* __restrict__ vfr, u16* __restrict__ part)
{
    __shared__ u16 buf[2][32][512];   // 64 KB

    const int i = blockIdx.x;
    const int b = (i >> 1) & 3;
    const int j = ((i >> 3) << 1) | (i & 1);    // segment 0..127

    const int w = threadIdx.x >> 6, lane = threadIdx.x & 63;
    const int q4 = lane >> 4, ln = lane & 15;

    const int u0 = (65 * j) >> 1;
    const int u1 = (65 * (j + 1)) >> 1;

    // decode g from u0: largest g with g*g+g <= u0
    int g = (int)((sqrtf((float)(4 * u0 + 1)) - 1.0f) * 0.5f);
    while ((g + 1) * (g + 2) <= u0) ++g;
    while (g * (g + 1) > u0) --g;
    int kt = u0 - g * (g + 1);
    int u = u0;

    // prologue: stage chunk kt into buf[u0&1]
    {
        const size_t cb = (size_t)((b * 128 + kt) * 16) * 512;
        #pragma unroll
        for (int c4 = 0; c4 < 8; ++c4) {
            const int c = w * 8 + c4;
            const u16* gsrc = ((c < 16) ? (kfr + cb + c * 512)
                                        : (vfr + cb + (c - 16) * 512)) + lane * 8;
            gl_lds(gsrc, &buf[u0 & 1][c][0]);
        }
    }

    while (u < u1) {
        const int tile16 = g * 4 + w;
        const int T = b * 256 + tile16;
        const int qg = tile16 * 16 + ln;
        const float inv = 1.0f / (float)(qg > 1 ? qg : 1);
        const int ktend = 2 * g + 2;
        const int kt_stop = (ktend < kt + (u1 - u)) ? ktend : (kt + (u1 - u));

        // Q B-frags for this g
        bf16x8 qB[8];
        {
            const u16* qb = qf + (size_t)(((b * 128 + (tile16 >> 1)) * 2 + (tile16 & 1)) * 8) * 512 + lane * 8;
            #pragma unroll
            for (int ks = 0; ks < 8; ++ks)
                qB[ks] = *(const bf16x8*)(qb + ks * 512);
        }

        f32x4 oacc[16];
        #pragma unroll
        for (int dt = 0; dt < 16; ++dt) oacc[dt] = f32x4{0.f, 0.f, 0.f, 0.f};

        #pragma unroll 1
        for (; kt < kt_stop; ++kt, ++u) {
            const int cur = u & 1;
            __syncthreads();   // drain this wave's prefetch; all chunks in LDS

            if (u + 1 < u1) {
                const int ktn = (kt + 1 < ktend) ? (kt + 1) : 0;
                const size_t cb = (size_t)((b * 128 + ktn) * 16) * 512;
                #pragma unroll
                for (int c4 = 0; c4 < 8; ++c4) {
                    const int c = w * 8 + c4;
                    const u16* gsrc = ((c < 16) ? (kfr + cb + c * 512)
                                                : (vfr + cb + (c - 16) * 512)) + lane * 8;
                    gl_lds(gsrc, &buf[cur ^ 1][c][0]);
                }
            }

            // ---- S^T = K Q^T ----
            f32x4 s0 = f32x4{0.f, 0.f, 0.f, 0.f};
            f32x4 s1 = f32x4{0.f, 0.f, 0.f, 0.f};
            #pragma unroll
            for (int ks = 0; ks < 8; ++ks) {
                bf16x8 kf0 = *(const bf16x8*)&buf[cur][ks][lane * 8];
                bf16x8 kf1 = *(const bf16x8*)&buf[cur][8 + ks][lane * 8];
                s0 = mfma32(kf0, qB[ks], s0);
                s1 = mfma32(kf1, qB[ks], s1);
            }

            // ---- mask/relu/scale, pack P^T (C-layout == K=16 B-frag) ----
            const int kb0 = kt * 32 + q4 * 4 - qg;
            bf16x4 p0, p1;
            #pragma unroll
            for (int rr = 0; rr < 4; ++rr) {
                float v0 = (kb0 + rr > 0) ? 0.f : fmaxf(s0[rr], 0.f) * inv;
                float v1 = (kb0 + 16 + rr > 0) ? 0.f : fmaxf(s1[rr], 0.f) * inv;
                p0[rr] = (short)f2b(v0);
                p1[rr] = (short)f2b(v1);
            }

            // ---- O^T += V^T P^T ----
            #pragma unroll
            for (int dt = 0; dt < 16; ++dt) {
                bf16x8 vv = *(const bf16x8*)&buf[cur][16 + dt][lane * 8];
                bf16x4 a0 = __builtin_shufflevector(vv, vv, 0, 1, 2, 3);
                bf16x4 a1 = __builtin_shufflevector(vv, vv, 4, 5, 6, 7);
                oacc[dt] = mfma16(a0, p0, oacc[dt]);
                oacc[dt] = mfma16(a1, p1, oacc[dt]);
            }
        }

        // ---- flush this g's partial: slot = j - j0(g), bf16 ----
        {
            const int j0g = (2 * (g * g + g) + 1) / 65;
            const int slot = j - j0g;
            u16* pb = part + ((size_t)(T * 5 + slot) * 16) * 256 + lane * 4;
            #pragma unroll
            for (int dt = 0; dt < 16; ++dt) {
                bf16x4 t;
                t[0] = (short)f2b(oacc[dt][0]); t[1] = (short)f2b(oacc[dt][1]);
                t[2] = (short)f2b(oacc[dt][2]); t[3] = (short)f2b(oacc[dt][3]);
                *(bf16x4*)(pb + dt * 256) = t;
            }
        }
        ++g;
        kt = 0;
    }
}

// ---------------------------------------------------------------------------
// Kernel 3: fused reduce + output projection. 512 blocks x 4 waves; block =
// 32 tokens. Phase A sums the valid bf16 partial slots (count from segment
// arithmetic) -> bf16 -> LDS (C-layout == K=16 B-frag). Phase B: out^T =
// Wo ctx^T via mfma16; direct fp32 stores (C-tile rows = 64B lines).
// ---------------------------------------------------------------------------
__global__ __launch_bounds__(256, 2) void oproj_kernel(
    const u16* __restrict__ part, const u16* __restrict__ wo16,
    float* __restrict__ out)
{
    __shared__ u16 cb[2 * 16 * 256];   // 16 KB

    const int w = threadIdx.x >> 6, lane = threadIdx.x & 63;
    const int q4 = lane >> 4, ln = lane & 15;
    const int g32 = blockIdx.x;        // 32-token group, 0..511
    const int g = (g32 & 127) >> 1;    // 64-query group within batch
    const int Ug2 = 2 * (g * g + g);
    const int j0g = (Ug2 + 1) / 65;
    const int jlast = (Ug2 + 2 * (2 * g + 1) + 1) / 65;
    const int nsl = jlast - j0g + 1;   // 1..5

    // Phase A: 32 chunks; wave w handles 8
    #pragma unroll
    for (int c4 = 0; c4 < 8; ++c4) {
        const int idx = w * 8 + c4;
        const int tokt = idx >> 4, dt = idx & 15;
        const int T = g32 * 2 + tokt;
        f32x4 s = f32x4{0.f, 0.f, 0.f, 0.f};
        for (int sl = 0; sl < nsl; ++sl) {
            bf16x4 pv = *(const bf16x4*)(part + ((size_t)(T * 5 + sl) * 16 + dt) * 256 + lane * 4);
            s[0] += b2f(pv[0]); s[1] += b2f(pv[1]);
            s[2] += b2f(pv[2]); s[3] += b2f(pv[3]);
        }
        bf16x4 t;
        t[0] = (short)f2b(s[0]); t[1] = (short)f2b(s[1]);
        t[2] = (short)f2b(s[2]); t[3] = (short)f2b(s[3]);
        *(bf16x4*)&cb[(tokt * 16 + dt) * 256 + lane * 4] = t;
    }
    __syncthreads();

    // Phase B: wave w -> d-tiles [w*4, w*4+4)
    #pragma unroll
    for (int c4 = 0; c4 < 4; ++c4) {
        const int ct = w * 4 + c4;
        f32x4 acc0 = f32x4{0.f, 0.f, 0.f, 0.f};
        f32x4 acc1 = f32x4{0.f, 0.f, 0.f, 0.f};
        #pragma unroll
        for (int dt = 0; dt < 16; ++dt) {
            bf16x4 A = *(const bf16x4*)(wo16 + (size_t)(ct * 16 + dt) * 256 + lane * 4);
            bf16x4 B0 = *(const bf16x4*)&cb[(0 * 16 + dt) * 256 + lane * 4];
            bf16x4 B1 = *(const bf16x4*)&cb[(1 * 16 + dt) * 256 + lane * 4];
            acc0 = mfma16(A, B0, acc0);
            acc1 = mfma16(A, B1, acc1);
        }
        float* o0 = out + (size_t)(g32 * 32 + 0 * 16 + ln) * DD + ct * 16 + q4 * 4;
        float* o1 = out + (size_t)(g32 * 32 + 1 * 16 + ln) * DD + ct * 16 + q4 * 4;
        *(f32x4*)o0 = acc0;
        *(f32x4*)o1 = acc1;
    }
}

extern "C" void kernel_launch(void* const* d_in, const int* in_sizes, int n_in,
                              void* d_out, int out_size, void* d_ws, size_t ws_size,
                              hipStream_t stream)
{
    const float* x  = (const float*)d_in[0];
    const float* Wq = (const float*)d_in[1];
    const float* Wk = (const float*)d_in[2];
    const float* Wv = (const float*)d_in[3];
    const float* Wo = (const float*)d_in[4];
    float* out = (float*)d_out;

    const size_t nW = (size_t)DD * DD;        // 65536
    const size_t nX = (size_t)BB * LL * DD;   // 4,194,304

    u16* wf   = (u16*)d_ws;                   // Wq,Wk,Wv B-frag order (384 KB)
    u16* wo16 = wf + 3 * nW;                  // Wo K=16 A-frag order (128 KB)
    u16* qfr  = wf + 4 * nW;                  // 8 MB
    u16* kfr  = qfr + nX;                     // 8 MB
    u16* vfr  = kfr + nX;                     // 8 MB
    u16* part = vfr + nX;                     // 1024*5*16*256 bf16 = 41.9 MB

    wconv_kernel<<<dim3(128), dim3(256), 0, stream>>>(Wq, Wk, Wv, Wo, wf, wo16);
    qkv_kernel<<<dim3(512), dim3(256), 0, stream>>>(x, wf, qfr, kfr, vfr);
    attn_kernel<<<dim3(512), dim3(256), 0, stream>>>(qfr, kfr, vfr, part);
    oproj_kernel<<<dim3(512), dim3(256), 0, stream>>>(part, wo16, out);
}